// Round 6
// baseline (843.682 us; speedup 1.0000x reference)
//
#include <hip/hip_runtime.h>
#include <math.h>

#define BSZ 32
#define NI  128

typedef __attribute__((ext_vector_type(8))) _Float16 f16x8;
typedef __attribute__((ext_vector_type(4))) _Float16 f16x4;
typedef __attribute__((ext_vector_type(4))) float    f32x4;

// MFMA16(X, Y, C): C[row = quad*4+reg <- X's l15][col = l15 <- Y's l15]
// X,Y k-index = quad*8 + j.
// Tiled operand format: 1KB tiles, inner l15*32 + quad*8 + j for a fragment.
#define MFMA16(a, b, c) __builtin_amdgcn_mfma_f32_16x16x32_f16((a), (b), (c), 0, 0, 0)

// global -> LDS async DMA, 16B per lane, wave-linear dest
#define GLL(g, l) __builtin_amdgcn_global_load_lds(                          \
    (const __attribute__((address_space(1))) void*)(g),                      \
    (__attribute__((address_space(3))) void*)(l), 16, 0, 0)

// barrier that waits LDS ops only (leaves global loads/stores in flight)
#define LGKM_BAR() do {                                                      \
    asm volatile("s_waitcnt lgkmcnt(0)" ::: "memory");                       \
    __builtin_amdgcn_sched_barrier(0);                                       \
    __builtin_amdgcn_s_barrier();                                            \
    __builtin_amdgcn_sched_barrier(0); } while (0)

__device__ inline float dot4f(float4 a, float4 b) {
    return a.x * b.x + a.y * b.y + a.z * b.z + a.w * b.w;
}

// swizzled pointer into row-major f32 LDS: row r, col c (multiple of 4).
__device__ inline float4* slp(float* base, int r, int c) {
    return (float4*)(base + r * 256 + ((((c) >> 2) ^ (r & 7)) << 2));
}

// ---------------------------------------------------------------------------
// 64x64 f32->f16 transpose tile -> TILED output (element (n,k) from src[k][n])
// ---------------------------------------------------------------------------
__device__ inline void tpose64(const float* __restrict__ src, int Csrc,
                               _Float16* __restrict__ dstT, int KT,
                               int r0, int c0, _Float16 (*tbuf)[72], int tid)
{
#pragma unroll
    for (int it = 0; it < 4; it++) {
        int idx = tid + it * 256;
        int rr = idx >> 4, c4 = idx & 15;
        float4 w = *(const float4*)(src + (size_t)(r0 + rr) * Csrc + c0 + c4 * 4);
        tbuf[c4 * 4 + 0][rr] = (_Float16)w.x;
        tbuf[c4 * 4 + 1][rr] = (_Float16)w.y;
        tbuf[c4 * 4 + 2][rr] = (_Float16)w.z;
        tbuf[c4 * 4 + 3][rr] = (_Float16)w.w;
    }
    __syncthreads();
#pragma unroll
    for (int it = 0; it < 2; it++) {
        int idx = tid + it * 256;
        int orr = idx >> 3, oc8 = idx & 7;
        int n = c0 + orr;
        size_t tile = (size_t)(n >> 4) * KT + (r0 >> 5) + (oc8 >> 2);
        *(f16x8*)(dstT + tile * 512 + (n & 15) * 32 + (oc8 & 3) * 8) = *(const f16x8*)&tbuf[orr][oc8 * 8];
    }
}

// ---------------------------------------------------------------------------
// prep: tiled f16 weights, qn, cls_n, qint2 = q@Wqi + bqi + bqs
// ---------------------------------------------------------------------------
__global__ __launch_bounds__(256) void prep(
    const float* __restrict__ Wk, const float* __restrict__ Wv,
    const float* __restrict__ Wqs, const float* __restrict__ Wf1,
    const float* __restrict__ Wf2,
    const float* __restrict__ intent_q, const float* __restrict__ Wqi,
    const float* __restrict__ bqi, const float* __restrict__ bqs,
    const float* __restrict__ cls_embed,
    _Float16* __restrict__ wkT, _Float16* __restrict__ wvT,
    _Float16* __restrict__ wqsT, _Float16* __restrict__ wf1T,
    _Float16* __restrict__ wf2T,
    float* __restrict__ qint2, float* __restrict__ qn, float* __restrict__ clsn)
{
    __shared__ _Float16 tbuf[64][72];
    __shared__ float buf[256];
    __shared__ float red[4];
    const int t = threadIdx.x, blk = blockIdx.x;
    const int lane = t & 63, w = t >> 6;

    if (blk < 112) {
        if (blk < 16)       tpose64(Wk, 256, wkT, 8, (blk >> 2) * 64, (blk & 3) * 64, tbuf, t);
        else if (blk < 32)  { int tt = blk - 16; tpose64(Wv, 256, wvT, 8, (tt >> 2) * 64, (tt & 3) * 64, tbuf, t); }
        else if (blk < 48)  { int tt = blk - 32; tpose64(Wqs, 256, wqsT, 8, (tt >> 2) * 64, (tt & 3) * 64, tbuf, t); }
        else if (blk < 80)  { int tt = blk - 48; tpose64(Wf1, 512, wf1T, 8, (tt & 3) * 64, (tt >> 2) * 64, tbuf, t); }
        else                { int tt = blk - 80; tpose64(Wf2, 256, wf2T, 16, (tt >> 2) * 64, (tt & 3) * 64, tbuf, t); }
    } else if (blk < 240) {
        int i = blk - 112;
        float x = intent_q[(size_t)i * 256 + t];
        buf[t] = x;
        float ss = x * x;
#pragma unroll
        for (int m = 1; m < 64; m <<= 1) ss += __shfl_xor(ss, m, 64);
        if (lane == 0) red[w] = ss;
        __syncthreads();
        float tot = red[0] + red[1] + red[2] + red[3];
        qn[(size_t)i * 256 + t] = x / fmaxf(sqrtf(tot), 1e-12f);
        float acc = bqi[t] + bqs[t];
        for (int e = 0; e < 256; e += 4) {
            const float4 q4 = *(const float4*)&buf[e];
            acc += q4.x * Wqi[(size_t)(e + 0) * 256 + t];
            acc += q4.y * Wqi[(size_t)(e + 1) * 256 + t];
            acc += q4.z * Wqi[(size_t)(e + 2) * 256 + t];
            acc += q4.w * Wqi[(size_t)(e + 3) * 256 + t];
        }
        qint2[(size_t)i * 256 + t] = acc;
    } else {
        int b = blk - 240;
        float x = cls_embed[(size_t)b * 256 + t];
        float ss = x * x;
#pragma unroll
        for (int m = 1; m < 64; m <<= 1) ss += __shfl_xor(ss, m, 64);
        if (lane == 0) red[w] = ss;
        __syncthreads();
        float tot = red[0] + red[1] + red[2] + red[3];
        clsn[(size_t)b * 256 + t] = x / fmaxf(sqrtf(tot), 1e-12f);
    }
}

// ---------------------------------------------------------------------------
// kvf_k: fused tokens->f16 + K-proj + V-proj. grid 256 x 512 threads.
// ---------------------------------------------------------------------------
__global__ __launch_bounds__(512, 2) void kvf_k(
    const float* __restrict__ tokens,
    const _Float16* __restrict__ wkT, const _Float16* __restrict__ wvT,
    const float* __restrict__ bk, const float* __restrict__ bv,
    _Float16* __restrict__ kT, _Float16* __restrict__ vT)
{
    __shared__ __align__(16) _Float16 Sb[2][8192];   // 2 x 16KB: 32 rows x 256d tiled

    const int t = threadIdx.x, lane = t & 63, w = t >> 6;
    const int l15 = lane & 15, quad = lane >> 4;
    const int lofs = l15 * 32 + quad * 8;
    const int lofsA = ((l15 * 4 + quad) ^ ((l15 >> 1) & 7)) * 8;
    const int bx = blockIdx.x;
    const int b = bx & 31, chunk = bx >> 5;

    f16x8 wk[2][8], wv[2][8];
#pragma unroll
    for (int j = 0; j < 2; j++)
#pragma unroll
        for (int ks = 0; ks < 8; ks++) {
            wk[j][ks] = *(const f16x8*)(wkT + ((size_t)(2 * w + j) * 8 + ks) * 512 + lofs);
            wv[j][ks] = *(const f16x8*)(wvT + ((size_t)(2 * w + j) * 8 + ks) * 512 + lofs);
        }
    f32x4 bi0 = *(const f32x4*)(bk + w * 32 + quad * 4);
    f32x4 bi1 = *(const f32x4*)(bk + w * 32 + 16 + quad * 4);
    const float bv0 = bv[(2 * w) * 16 + l15];
    const float bv1 = bv[(2 * w + 1) * 16 + l15];

    const int rr = t >> 5, d8 = t & 31;
    const float* tbase = tokens + ((size_t)b * 2048 + chunk * 256) * 256 + rr * 256 + d8 * 8;
    const int mskW = ((rr >> 1) & 7) ^ (((d8 >> 2) & 3) << 1);
    const int wofs0 = (d8 >> 2) * 512 + (((rr * 4 + (d8 & 3)) ^ mskW) * 8);
    const int wofs1 = wofs0 + 8 * 512;

    float4 pa0, pa1, pb0, pb1;

#define KVF_LOADS(P) do {                                                    \
        const float* sp_ = tbase + (size_t)(P) * 8192;                       \
        pa0 = *(const float4*)(sp_);                                         \
        pa1 = *(const float4*)(sp_ + 4);                                     \
        pb0 = *(const float4*)(sp_ + 4096);                                  \
        pb1 = *(const float4*)(sp_ + 4100);                                  \
    } while (0)

#define KVF_STAGE(BUF) do {                                                  \
        f16x8 h0, h1;                                                        \
        h0[0] = (_Float16)pa0.x; h0[1] = (_Float16)pa0.y;                    \
        h0[2] = (_Float16)pa0.z; h0[3] = (_Float16)pa0.w;                    \
        h0[4] = (_Float16)pa1.x; h0[5] = (_Float16)pa1.y;                    \
        h0[6] = (_Float16)pa1.z; h0[7] = (_Float16)pa1.w;                    \
        h1[0] = (_Float16)pb0.x; h1[1] = (_Float16)pb0.y;                    \
        h1[2] = (_Float16)pb0.z; h1[3] = (_Float16)pb0.w;                    \
        h1[4] = (_Float16)pb1.x; h1[5] = (_Float16)pb1.y;                    \
        h1[6] = (_Float16)pb1.z; h1[7] = (_Float16)pb1.w;                    \
        *(f16x8*)((BUF) + wofs0) = h0;                                       \
        *(f16x8*)((BUF) + wofs1) = h1;                                       \
    } while (0)

    KVF_LOADS(0);
    KVF_STAGE(&Sb[0][0]);
    LGKM_BAR();

    for (int p = 0; p < 8; p++) {
        if (p < 7) KVF_LOADS(p + 1);
        __builtin_amdgcn_sched_barrier(0);

        const _Float16* lb = &Sb[p & 1][0];
        const int stg0 = chunk * 16 + p * 2;
        const int sp = chunk * 8 + p;

        f16x8 a[2][8];
#pragma unroll
        for (int st = 0; st < 2; st++)
#pragma unroll
            for (int ks = 0; ks < 8; ks++)
                a[st][ks] = *(const f16x8*)(lb + (st * 8 + ks) * 512 + (lofsA ^ ((ks & 3) * 16)));

        // K: c[row=dim][col=seq]
#pragma unroll
        for (int st = 0; st < 2; st++) {
            f32x4 c0 = {0.f, 0.f, 0.f, 0.f}, c1 = {0.f, 0.f, 0.f, 0.f};
#pragma unroll
            for (int ks = 0; ks < 8; ks++) {
                c0 = MFMA16(wk[0][ks], a[st][ks], c0);
                c1 = MFMA16(wk[1][ks], a[st][ks], c1);
            }
            f16x4 p0, p1;
#pragma unroll
            for (int reg = 0; reg < 4; reg++) {
                p0[reg] = (_Float16)(c0[reg] + bi0[reg]);
                p1[reg] = (_Float16)(c1[reg] + bi1[reg]);
            }
            _Float16* tp = kT + ((size_t)(b * 128 + stg0 + st) * 8 + w) * 512 + l15 * 32;
            *(f16x4*)(tp + (quad >> 1) * 8 + (quad & 1) * 4) = p0;
            *(f16x4*)(tp + (2 + (quad >> 1)) * 8 + (quad & 1) * 4) = p1;
        }

        // V: c[row=seq][col=dim]
#pragma unroll
        for (int j = 0; j < 2; j++) {
            f32x4 c0 = {0.f, 0.f, 0.f, 0.f}, c1 = {0.f, 0.f, 0.f, 0.f};
#pragma unroll
            for (int ks = 0; ks < 8; ks++) {
                c0 = MFMA16(a[0][ks], wv[j][ks], c0);
                c1 = MFMA16(a[1][ks], wv[j][ks], c1);
            }
            const float bb = j ? bv1 : bv0;
            f16x4 p0, p1;
#pragma unroll
            for (int reg = 0; reg < 4; reg++) {
                p0[reg] = (_Float16)(c0[reg] + bb);
                p1[reg] = (_Float16)(c1[reg] + bb);
            }
            _Float16* tp = vT + ((size_t)(b * 16 + 2 * w + j) * 64 + sp) * 512 + l15 * 32;
            *(f16x4*)(tp + (quad >> 1) * 8 + (quad & 1) * 4) = p0;
            *(f16x4*)(tp + (2 + (quad >> 1)) * 8 + (quad & 1) * 4) = p1;
        }

        if (p < 7) {
            KVF_STAGE(&Sb[(p + 1) & 1][0]);
            LGKM_BAR();
        }
    }
#undef KVF_LOADS
#undef KVF_STAGE
}

// ---------------------------------------------------------------------------
// qs phase (shared by init + per-iter): qs = (sl@Wqs + qint2)/16 -> qsA tiled.
// pair (rt, h): h picks 8 of 16 d-tiles. Conversion order identical to the
// old qslot/mlp-4a path.
// ---------------------------------------------------------------------------
__device__ inline void qs_phase(float* sl, _Float16* qsA,
                                const _Float16* __restrict__ wqsT,
                                const float* __restrict__ qint2,
                                int rt, int h, int l15, int quad, int lofs, int R0)
{
    const int lrf = rt * 16 + l15;
    f16x8 bs[8];
#pragma unroll
    for (int ks = 0; ks < 8; ks++) {
        const int c0 = ks * 32 + quad * 8;
        float4 xa = *slp(sl, lrf, c0);
        float4 xb = *slp(sl, lrf, c0 + 4);
        bs[ks][0] = (_Float16)xa.x; bs[ks][1] = (_Float16)xa.y;
        bs[ks][2] = (_Float16)xa.z; bs[ks][3] = (_Float16)xa.w;
        bs[ks][4] = (_Float16)xb.x; bs[ks][5] = (_Float16)xb.y;
        bs[ks][6] = (_Float16)xb.z; bs[ks][7] = (_Float16)xb.w;
    }
    const int iq = ((R0 + lrf) >> 2) & 127;
#pragma unroll
    for (int d = 0; d < 8; d++) {
        const int dti = h * 8 + d;
        f32x4 c = {0.f, 0.f, 0.f, 0.f};
#pragma unroll
        for (int ks = 0; ks < 8; ks++)
            c = MFMA16(*(const f16x8*)(wqsT + ((size_t)dti * 8 + ks) * 512 + lofs), bs[ks], c);
        float4 qi = *(const float4*)(qint2 + (size_t)iq * 256 + dti * 16 + quad * 4);
        f16x4 o;
#pragma unroll
        for (int reg = 0; reg < 4; reg++) o[reg] = (_Float16)((c[reg] + qi[reg]) * 0.0625f);
        *(f16x4*)(qsA + rt * 4096 + (dti >> 1) * 512 + l15 * 32
                  + ((dti & 1) * 2 + (quad >> 1)) * 8 + (quad & 1) * 4) = o;
    }
}

// ---------------------------------------------------------------------------
// mega_k: slots-init + 3x{attention sweep + LN1/LN2/FFN1/FFN2 + qs} + final.
// grid 256 x 512: b = bx&31 (XCD b%8 matches kvf), rg = bx>>5; 64 rows/block.
// Rows are independent across the whole iterate loop -> zero global traffic
// for slots/O/psum/qs. waves: (rt 0..3 = 16-row tile, h 0..1 = key-half in QK
// and dim-half in PV). O accumulates f32 in regs over all 2048 keys.
// ---------------------------------------------------------------------------
__global__ __launch_bounds__(512, 2) void mega_k(
    const _Float16* __restrict__ kT, const _Float16* __restrict__ vT,
    const float* __restrict__ noise, const float* __restrict__ slot_mu,
    const float* __restrict__ slot_sigma,
    const _Float16* __restrict__ wqsT, const float* __restrict__ qint2,
    const float* __restrict__ ln1_g, const float* __restrict__ ln1_b,
    const float* __restrict__ ln2_g, const float* __restrict__ ln2_b,
    const _Float16* __restrict__ wf1T, const float* __restrict__ bf1,
    const _Float16* __restrict__ wf2T, const float* __restrict__ bf2,
    const float* __restrict__ qn, const float* __restrict__ clsn,
    const float* __restrict__ alphap, const float* __restrict__ tempp,
    float* __restrict__ out)
{
    __shared__ float sl[64 * 256];                  // 64KB slots/x1, swizzled
    __shared__ __align__(16) char arena[65536];     // Kb|Vb|pb / qs / Obuf / act
    __shared__ float2 st2[64];
    __shared__ float psb[2][64];

    _Float16* KbA  = (_Float16*)arena;              // [2][8192]  32KB
    _Float16* VbA  = (_Float16*)(arena + 32768);    // [8192]     16KB
    _Float16* pbA  = (_Float16*)(arena + 49152);    // [4][640]    5KB
    float*    Obuf = (float*)arena;                 // [64][256]  64KB
    _Float16* qsA  = (_Float16*)arena;              // [4][4096]  32KB
    _Float16* actA = (_Float16*)arena;              // [4][8192]  64KB

    const int tid = threadIdx.x, lane = tid & 63, wvid = tid >> 6;
    const int l15 = lane & 15, quad = lane >> 4;
    const int lofs = l15 * 32 + quad * 8;
    const int lofsA = ((l15 * 4 + quad) ^ ((l15 >> 1) & 7)) * 8;
    const int lnsw = (lane ^ ((lane >> 3) & 7)) * 8;
    const int bx = blockIdx.x;
    const int b = bx & 31, rg = bx >> 5;
    const int R0 = b * 512 + rg * 64;
    const int rt = wvid >> 1, h = wvid & 1;

    // ---------------- slots init: sl = mu + eps*sigma ----------------
    {
        const int lr = tid >> 3, f = tid & 7;
        const int gr = R0 + lr;
        const int ii = (gr >> 2) & 127, n = gr & 3;
        const float* np = noise + (((size_t)ii * BSZ + b) * 4 + n) * 256;
#pragma unroll
        for (int j = 0; j < 8; j++) {
            const int c = f * 32 + j * 4;
            float4 mu = *(const float4*)(slot_mu + n * 256 + c);
            float4 sg = *(const float4*)(slot_sigma + n * 256 + c);
            float4 ns = *(const float4*)(np + c);
            float4 o;
            o.x = mu.x + ns.x * sg.x; o.y = mu.y + ns.y * sg.y;
            o.z = mu.z + ns.z * sg.z; o.w = mu.w + ns.w * sg.w;
            *slp(sl, lr, c) = o;
        }
    }
    __syncthreads();

    qs_phase(sl, qsA, wqsT, qint2, rt, h, l15, quad, lofs, R0);
    __syncthreads();

    for (int it = 0; it < 3; it++) {
        // ---- load q fragments for this wave's 16 rows, then free arena ----
        f16x8 q[8];
#pragma unroll
        for (int ks = 0; ks < 8; ks++)
            q[ks] = *(const f16x8*)(qsA + rt * 4096 + ks * 512 + lofs);
        __syncthreads();

        f32x4 O[8];
#pragma unroll
        for (int d = 0; d < 8; d++) O[d] = (f32x4){0.f, 0.f, 0.f, 0.f};
        float ps[4] = {0.f, 0.f, 0.f, 0.f};

        // prologue: K(0)
#pragma unroll
        for (int j = 0; j < 2; j++) {
            const int e = wvid * 2 + j;
            GLL(kT + ((size_t)(b * 128 + (e >> 3)) * 8 + (e & 7)) * 512 + lnsw,
                KbA + e * 512 + lane * 8);
        }
        asm volatile("s_waitcnt vmcnt(0)" ::: "memory");
        __builtin_amdgcn_s_barrier();
        __builtin_amdgcn_sched_barrier(0);

        for (int ss = 0; ss < 64; ss++) {
            const int cur = ss & 1;
            // stage V(ss)
#pragma unroll
            for (int j = 0; j < 2; j++) {
                const int e = wvid * 2 + j;
                GLL(vT + ((size_t)(b * 16 + e) * 64 + ss) * 512 + lnsw,
                    VbA + e * 512 + lane * 8);
            }
            if (ss < 63) {
#pragma unroll
                for (int j = 0; j < 2; j++) {
                    const int e = wvid * 2 + j;
                    GLL(kT + ((size_t)(b * 128 + (ss + 1) * 2 + (e >> 3)) * 8 + (e & 7)) * 512 + lnsw,
                        KbA + (cur ^ 1) * 8192 + e * 512 + lane * 8);
                }
                asm volatile("s_waitcnt vmcnt(4)" ::: "memory");
            } else {
                asm volatile("s_waitcnt vmcnt(2)" ::: "memory");
            }
            __builtin_amdgcn_s_barrier();
            __builtin_amdgcn_sched_barrier(0);

            // QK on key-16-tile h of Kb[cur]
            {
                const _Float16* kp = KbA + cur * 8192 + (h * 8) * 512;
                f32x4 c0 = {0.f, 0.f, 0.f, 0.f};
#pragma unroll
                for (int ks = 0; ks < 8; ks++)
                    c0 = MFMA16(q[ks], *(const f16x8*)(kp + ks * 512 + lofsA), c0);
                _Float16* pw = pbA + rt * 640;
#pragma unroll
                for (int reg = 0; reg < 4; reg++) {
                    float p0 = __expf(fminf(c0[reg], 10.5f));
                    ps[reg] += p0;
                    pw[(quad * 4 + reg) * 40 + h * 16 + l15] = (_Float16)p0;
                }
            }
            __builtin_amdgcn_sched_barrier(0);
            asm volatile("s_waitcnt lgkmcnt(0)" ::: "memory");   // P visible cross-wave
            if (ss < 63) {
                asm volatile("s_waitcnt vmcnt(2)" ::: "memory"); // V landed, K flying
            } else {
                asm volatile("s_waitcnt vmcnt(0)" ::: "memory");
            }
            __builtin_amdgcn_s_barrier();
            __builtin_amdgcn_sched_barrier(0);

            // PV: dims h*128..h*128+128 over the 32 staged keys
            {
                const _Float16* pw = pbA + rt * 640;
                f16x8 pa = *(const f16x8*)(pw + l15 * 40 + quad * 8);
#pragma unroll
                for (int d = 0; d < 8; d++) {
                    const _Float16* vp = VbA + (h * 8 + d) * 512;
                    O[d] = MFMA16(pa, *(const f16x8*)(vp + lofsA), O[d]);
                }
            }
            __builtin_amdgcn_sched_barrier(0);
            __builtin_amdgcn_s_barrier();
            __builtin_amdgcn_sched_barrier(0);
        }

        // ---- psum reduce (over l15 keys axis), per key-half ----
#pragma unroll
        for (int msk = 1; msk <= 8; msk <<= 1)
#pragma unroll
            for (int reg = 0; reg < 4; reg++) ps[reg] += __shfl_xor(ps[reg], msk, 64);
        if (l15 == 0) {
#pragma unroll
            for (int reg = 0; reg < 4; reg++)
                psb[h][rt * 16 + quad * 4 + reg] = ps[reg];
        }
        __syncthreads();          // attn done; arena becomes Obuf

        // ---- O -> Obuf (f32, swizzled); dims disjoint per wave ----
#pragma unroll
        for (int d = 0; d < 8; d++) {
            const int dt = h * 8 + d;
#pragma unroll
            for (int reg = 0; reg < 4; reg++) {
                const int row = rt * 16 + quad * 4 + reg;
                const int c = dt * 16 + l15;
                Obuf[row * 256 + ((((c >> 2) ^ (row & 7)) << 2) | (c & 3))] = O[d][reg];
            }
        }
        __syncthreads();

        // ---- phase 1: y = slots + O/l; x1 = LN1(y) -> sl; LN2 stats ----
#pragma unroll
        for (int r2 = 0; r2 < 2; r2++) {
            const int lr = rt * 16 + h * 8 + r2 * 4 + quad;
            const float l = psb[0][lr] + psb[1][lr];
            const float invl = 1.f / l;
            float4 y[4];
            float sm = 0.f, sq = 0.f;
#pragma unroll
            for (int k = 0; k < 4; k++) {
                const int c = k * 64 + l15 * 4;
                float4 o4 = *slp(Obuf, lr, c);
                float4 s4 = *slp(sl, lr, c);
                y[k].x = s4.x + o4.x * invl; y[k].y = s4.y + o4.y * invl;
                y[k].z = s4.z + o4.z * invl; y[k].w = s4.w + o4.w * invl;
                sm += y[k].x + y[k].y + y[k].z + y[k].w;
                sq += dot4f(y[k], y[k]);
            }
#pragma unroll
            for (int m = 1; m <= 8; m <<= 1) { sm += __shfl_xor(sm, m, 64); sq += __shfl_xor(sq, m, 64); }
            const float mean = sm * (1.f / 256.f);
            const float rstd = rsqrtf(sq * (1.f / 256.f) - mean * mean + 1e-5f);
            float sm2 = 0.f, sq2 = 0.f;
#pragma unroll
            for (int k = 0; k < 4; k++) {
                const int c = k * 64 + l15 * 4;
                float4 g1 = *(const float4*)(ln1_g + c);
                float4 b1 = *(const float4*)(ln1_b + c);
                float4 x1;
                x1.x = (y[k].x - mean) * rstd * g1.x + b1.x;
                x1.y = (y[k].y - mean) * rstd * g1.y + b1.y;
                x1.z = (y[k].z - mean) * rstd * g1.z + b1.z;
                x1.w = (y[k].w - mean) * rstd * g1.w + b1.w;
                *slp(sl, lr, c) = x1;
                sm2 += x1.x + x1.y + x1.z + x1.w;
                sq2 += dot4f(x1, x1);
            }
#pragma unroll
            for (int m = 1; m <= 8; m <<= 1) { sm2 += __shfl_xor(sm2, m, 64); sq2 += __shfl_xor(sq2, m, 64); }
            const float mean2 = sm2 * (1.f / 256.f);
            const float rstd2 = rsqrtf(sq2 * (1.f / 256.f) - mean2 * mean2 + 1e-5f);
            if (l15 == 0) st2[lr] = make_float2(mean2, rstd2);
        }
        __syncthreads();          // Obuf dead; arena becomes actA

        // ---- phase 2: act = gelu(LN2(x1)@Wf1+bf1) -> actA (swizzled) ----
        const int lrf = rt * 16 + l15;
        {
            const float2 s2 = st2[lrf];
            f16x8 bh[8];
#pragma unroll
            for (int ks = 0; ks < 8; ks++) {
                const int c0 = ks * 32 + quad * 8;
                float4 xa = *slp(sl, lrf, c0);
                float4 xb = *slp(sl, lrf, c0 + 4);
                float4 ga = *(const float4*)(ln2_g + c0);
                float4 gb = *(const float4*)(ln2_g + c0 + 4);
                float4 ba = *(const float4*)(ln2_b + c0);
                float4 bb2 = *(const float4*)(ln2_b + c0 + 4);
                bh[ks][0] = (_Float16)((xa.x - s2.x) * s2.y * ga.x + ba.x);
                bh[ks][1] = (_Float16)((xa.y - s2.x) * s2.y * ga.y + ba.y);
                bh[ks][2] = (_Float16)((xa.z - s2.x) * s2.y * ga.z + ba.z);
                bh[ks][3] = (_Float16)((xa.w - s2.x) * s2.y * ga.w + ba.w);
                bh[ks][4] = (_Float16)((xb.x - s2.x) * s2.y * gb.x + bb2.x);
                bh[ks][5] = (_Float16)((xb.y - s2.x) * s2.y * gb.y + bb2.y);
                bh[ks][6] = (_Float16)((xb.z - s2.x) * s2.y * gb.z + bb2.z);
                bh[ks][7] = (_Float16)((xb.w - s2.x) * s2.y * gb.w + bb2.w);
            }
#pragma unroll 2
            for (int t16 = 0; t16 < 16; t16++) {
                const int hti = h * 16 + t16;
                f32x4 c = {0.f, 0.f, 0.f, 0.f};
#pragma unroll
                for (int ks = 0; ks < 8; ks++)
                    c = MFMA16(*(const f16x8*)(wf1T + ((size_t)hti * 8 + ks) * 512 + lofs), bh[ks], c);
                float4 bb = *(const float4*)(bf1 + hti * 16 + quad * 4);
                f16x4 o;
#pragma unroll
                for (int reg = 0; reg < 4; reg++) {
                    float xg = c[reg] + bb[reg];
                    o[reg] = (_Float16)(0.5f * xg * (1.f + erff(xg * 0.70710678118654752f)));
                }
                const int gA = l15 * 4 + (hti & 1) * 2 + (quad >> 1);
                *(f16x4*)(actA + rt * 8192 + ((size_t)(hti >> 1)) * 512
                          + ((gA ^ ((l15 >> 1) & 7)) * 8) + (quad & 1) * 4) = o;
            }
        }
        __syncthreads();

        // ---- phase 3: slots_new = x1 + act@Wf2 + bf2 -> sl ----
        {
            f32x4 c[8];
#pragma unroll
            for (int d = 0; d < 8; d++) {
                const int dti = h * 8 + d;
                float4 x4 = *slp(sl, lrf, dti * 16 + quad * 4);
                float4 bb = *(const float4*)(bf2 + dti * 16 + quad * 4);
                c[d] = (f32x4){x4.x + bb.x, x4.y + bb.y, x4.z + bb.z, x4.w + bb.w};
            }
            for (int ks = 0; ks < 16; ks++) {
                f16x8 afrag = *(const f16x8*)(actA + rt * 8192 + (size_t)ks * 512 + lofsA);
#pragma unroll
                for (int d = 0; d < 8; d++)
                    c[d] = MFMA16(*(const f16x8*)(wf2T + ((size_t)(h * 8 + d) * 16 + ks) * 512 + lofs),
                                  afrag, c[d]);
            }
            __syncthreads();   // all x1 reads done before overwrite
#pragma unroll
            for (int d = 0; d < 8; d++) {
                const int dti = h * 8 + d;
                float4 v = {c[d][0], c[d][1], c[d][2], c[d][3]};
                *slp(sl, lrf, dti * 16 + quad * 4) = v;
            }
        }
        __syncthreads();

        if (it < 2) {
            qs_phase(sl, qsA, wqsT, qint2, rt, h, l15, quad, lofs, R0);
            __syncthreads();
        }
    }

    // ---------------- final scoring: 16 intents, 2 per wave ----------------
#pragma unroll
    for (int ii = 0; ii < 2; ii++) {
        const int i_loc = wvid * 2 + ii;
        const int i = rg * 16 + i_loc;
        float4 qv = *(const float4*)(qn + (size_t)i * 256 + lane * 4);
        float4 xs[4];
        float st4[4];
#pragma unroll
        for (int n = 0; n < 4; n++) {
            xs[n] = *slp(sl, i_loc * 4 + n, lane * 4);
            float ss = dot4f(xs[n], xs[n]);
            float sq = dot4f(xs[n], qv);
#pragma unroll
            for (int m = 1; m < 64; m <<= 1) { ss += __shfl_xor(ss, m, 64); sq += __shfl_xor(sq, m, 64); }
            st4[n] = sq / fmaxf(sqrtf(ss), 1e-12f);
        }
        float mx = fmaxf(fmaxf(st4[0], st4[1]), fmaxf(st4[2], st4[3]));
        float e0 = __expf(st4[0] - mx), e1 = __expf(st4[1] - mx);
        float e2 = __expf(st4[2] - mx), e3 = __expf(st4[3] - mx);
        float inv = 1.f / (e0 + e1 + e2 + e3);
        float4 smv;
        smv.x = (e0 * xs[0].x + e1 * xs[1].x + e2 * xs[2].x + e3 * xs[3].x) * inv;
        smv.y = (e0 * xs[0].y + e1 * xs[1].y + e2 * xs[2].y + e3 * xs[3].y) * inv;
        smv.z = (e0 * xs[0].z + e1 * xs[1].z + e2 * xs[2].z + e3 * xs[3].z) * inv;
        smv.w = (e0 * xs[0].w + e1 * xs[1].w + e2 * xs[2].w + e3 * xs[3].w) * inv;
        float ssm = dot4f(smv, smv);
        float sqn = dot4f(smv, qv);
        float4 cv = *(const float4*)(clsn + (size_t)b * 256 + lane * 4);
        float cq = dot4f(cv, qv);
#pragma unroll
        for (int m = 1; m < 64; m <<= 1) {
            ssm += __shfl_xor(ssm, m, 64);
            sqn += __shfl_xor(sqn, m, 64);
            cq  += __shfl_xor(cq,  m, 64);
        }
        if (lane == 0) {
            float score = cq + alphap[0] * sqn / fmaxf(sqrtf(ssm), 1e-12f);
            out[(size_t)b * NI + i] = score / fmaxf(tempp[0], 1e-4f);
        }
    }
}

// ---------------------------------------------------------------------------
extern "C" void kernel_launch(void* const* d_in, const int* in_sizes, int n_in,
                              void* d_out, int out_size, void* d_ws, size_t ws_size,
                              hipStream_t stream)
{
    const float* tokens     = (const float*)d_in[0];
    const float* cls_embed  = (const float*)d_in[1];
    const float* intent_q   = (const float*)d_in[2];
    const float* noise      = (const float*)d_in[3];
    const float* Wk  = (const float*)d_in[4];
    const float* bk  = (const float*)d_in[5];
    const float* Wv  = (const float*)d_in[6];
    const float* bv  = (const float*)d_in[7];
    const float* Wqs = (const float*)d_in[8];
    const float* bqs = (const float*)d_in[9];
    const float* Wqi = (const float*)d_in[10];
    const float* bqi = (const float*)d_in[11];
    const float* ln1g = (const float*)d_in[12];
    const float* ln1b = (const float*)d_in[13];
    const float* ln2g = (const float*)d_in[14];
    const float* ln2b = (const float*)d_in[15];
    const float* Wf1 = (const float*)d_in[16];
    const float* bf1 = (const float*)d_in[17];
    const float* Wf2 = (const float*)d_in[18];
    const float* bf2 = (const float*)d_in[19];
    const float* slot_mu    = (const float*)d_in[20];
    const float* slot_sigma = (const float*)d_in[21];
    const float* alphap = (const float*)d_in[22];
    const float* tempp  = (const float*)d_in[23];
    float* out = (float*)d_out;

    char* base = (char*)d_ws;
    _Float16* kT    = (_Float16*)(base + 33554432u);            // 33554432 B
    _Float16* vT    = (_Float16*)(base + 67108864u);            // 33554432 B
    _Float16* wkT   = (_Float16*)(base + 150994944u);           //   131072 B
    _Float16* wvT   = (_Float16*)(base + 151126016u);
    _Float16* wqsT  = (_Float16*)(base + 151257088u);
    _Float16* wf1T  = (_Float16*)(base + 151388160u);           //   262144 B
    _Float16* wf2T  = (_Float16*)(base + 151650304u);           //   262144 B
    float* qint2    = (float*)(base + 151912448u);              //   131072 B
    float* qnb      = (float*)(base + 152043520u);              //   131072 B
    float* clsn     = (float*)(base + 152174592u);              //    32768 B

    prep<<<272, 256, 0, stream>>>(Wk, Wv, Wqs, Wf1, Wf2, intent_q, Wqi, bqi, bqs,
                                  cls_embed, wkT, wvT, wqsT, wf1T, wf2T,
                                  qint2, qnb, clsn);
    kvf_k<<<256, 512, 0, stream>>>(tokens, wkT, wvT, bk, bv, kT, vT);
    mega_k<<<256, 512, 0, stream>>>(kT, vT, noise, slot_mu, slot_sigma,
                                    wqsT, qint2,
                                    ln1g, ln1b, ln2g, ln2b,
                                    wf1T, bf1, wf2T, bf2,
                                    qnb, clsn, alphap, tempp, out);
}

// Round 7
// 489.253 us; speedup vs baseline: 1.7244x; 1.7244x over previous
//
#include <hip/hip_runtime.h>
#include <math.h>

#define BSZ 32
#define NI  128

typedef __attribute__((ext_vector_type(8))) _Float16 f16x8;
typedef __attribute__((ext_vector_type(4))) _Float16 f16x4;
typedef __attribute__((ext_vector_type(4))) float    f32x4;

// MFMA16(X, Y, C): C[row = quad*4+reg <- X's l15][col = l15 <- Y's l15]
// X,Y k-index = quad*8 + j.
// Tiled operand format: 1KB tiles, inner l15*32 + quad*8 + j for a fragment.
#define MFMA16(a, b, c) __builtin_amdgcn_mfma_f32_16x16x32_f16((a), (b), (c), 0, 0, 0)

// global -> LDS async DMA, 16B per lane, wave-linear dest
#define GLL(g, l) __builtin_amdgcn_global_load_lds(                          \
    (const __attribute__((address_space(1))) void*)(g),                      \
    (__attribute__((address_space(3))) void*)(l), 16, 0, 0)

// barrier that waits LDS ops only (leaves global loads/stores in flight)
#define LGKM_BAR() do {                                                      \
    asm volatile("s_waitcnt lgkmcnt(0)" ::: "memory");                       \
    __builtin_amdgcn_sched_barrier(0);                                       \
    __builtin_amdgcn_s_barrier();                                            \
    __builtin_amdgcn_sched_barrier(0); } while (0)

__device__ inline float dot4f(float4 a, float4 b) {
    return a.x * b.x + a.y * b.y + a.z * b.z + a.w * b.w;
}

// swizzled pointer into row-major f32 LDS: row r, col c (multiple of 4).
__device__ inline float4* slp(float* base, int r, int c) {
    return (float4*)(base + r * 256 + ((((c) >> 2) ^ (r & 7)) << 2));
}

// ---------------------------------------------------------------------------
// 64x64 f32->f16 transpose tile -> TILED output (element (n,k) from src[k][n])
// ---------------------------------------------------------------------------
__device__ inline void tpose64(const float* __restrict__ src, int Csrc,
                               _Float16* __restrict__ dstT, int KT,
                               int r0, int c0, _Float16 (*tbuf)[72], int tid)
{
#pragma unroll
    for (int it = 0; it < 4; it++) {
        int idx = tid + it * 256;
        int rr = idx >> 4, c4 = idx & 15;
        float4 w = *(const float4*)(src + (size_t)(r0 + rr) * Csrc + c0 + c4 * 4);
        tbuf[c4 * 4 + 0][rr] = (_Float16)w.x;
        tbuf[c4 * 4 + 1][rr] = (_Float16)w.y;
        tbuf[c4 * 4 + 2][rr] = (_Float16)w.z;
        tbuf[c4 * 4 + 3][rr] = (_Float16)w.w;
    }
    __syncthreads();
#pragma unroll
    for (int it = 0; it < 2; it++) {
        int idx = tid + it * 256;
        int orr = idx >> 3, oc8 = idx & 7;
        int n = c0 + orr;
        size_t tile = (size_t)(n >> 4) * KT + (r0 >> 5) + (oc8 >> 2);
        *(f16x8*)(dstT + tile * 512 + (n & 15) * 32 + (oc8 & 3) * 8) = *(const f16x8*)&tbuf[orr][oc8 * 8];
    }
}

// ---------------------------------------------------------------------------
// prep: tiled f16 weights, qn, cls_n, qint2 = q@Wqi + bqi + bqs
// ---------------------------------------------------------------------------
__global__ __launch_bounds__(256) void prep(
    const float* __restrict__ Wk, const float* __restrict__ Wv,
    const float* __restrict__ Wqs, const float* __restrict__ Wf1,
    const float* __restrict__ Wf2,
    const float* __restrict__ intent_q, const float* __restrict__ Wqi,
    const float* __restrict__ bqi, const float* __restrict__ bqs,
    const float* __restrict__ cls_embed,
    _Float16* __restrict__ wkT, _Float16* __restrict__ wvT,
    _Float16* __restrict__ wqsT, _Float16* __restrict__ wf1T,
    _Float16* __restrict__ wf2T,
    float* __restrict__ qint2, float* __restrict__ qn, float* __restrict__ clsn)
{
    __shared__ _Float16 tbuf[64][72];
    __shared__ float buf[256];
    __shared__ float red[4];
    const int t = threadIdx.x, blk = blockIdx.x;
    const int lane = t & 63, w = t >> 6;

    if (blk < 112) {
        if (blk < 16)       tpose64(Wk, 256, wkT, 8, (blk >> 2) * 64, (blk & 3) * 64, tbuf, t);
        else if (blk < 32)  { int tt = blk - 16; tpose64(Wv, 256, wvT, 8, (tt >> 2) * 64, (tt & 3) * 64, tbuf, t); }
        else if (blk < 48)  { int tt = blk - 32; tpose64(Wqs, 256, wqsT, 8, (tt >> 2) * 64, (tt & 3) * 64, tbuf, t); }
        else if (blk < 80)  { int tt = blk - 48; tpose64(Wf1, 512, wf1T, 8, (tt & 3) * 64, (tt >> 2) * 64, tbuf, t); }
        else                { int tt = blk - 80; tpose64(Wf2, 256, wf2T, 16, (tt >> 2) * 64, (tt & 3) * 64, tbuf, t); }
    } else if (blk < 240) {
        int i = blk - 112;
        float x = intent_q[(size_t)i * 256 + t];
        buf[t] = x;
        float ss = x * x;
#pragma unroll
        for (int m = 1; m < 64; m <<= 1) ss += __shfl_xor(ss, m, 64);
        if (lane == 0) red[w] = ss;
        __syncthreads();
        float tot = red[0] + red[1] + red[2] + red[3];
        qn[(size_t)i * 256 + t] = x / fmaxf(sqrtf(tot), 1e-12f);
        float acc = bqi[t] + bqs[t];
        for (int e = 0; e < 256; e += 4) {
            const float4 q4 = *(const float4*)&buf[e];
            acc += q4.x * Wqi[(size_t)(e + 0) * 256 + t];
            acc += q4.y * Wqi[(size_t)(e + 1) * 256 + t];
            acc += q4.z * Wqi[(size_t)(e + 2) * 256 + t];
            acc += q4.w * Wqi[(size_t)(e + 3) * 256 + t];
        }
        qint2[(size_t)i * 256 + t] = acc;
    } else {
        int b = blk - 240;
        float x = cls_embed[(size_t)b * 256 + t];
        float ss = x * x;
#pragma unroll
        for (int m = 1; m < 64; m <<= 1) ss += __shfl_xor(ss, m, 64);
        if (lane == 0) red[w] = ss;
        __syncthreads();
        float tot = red[0] + red[1] + red[2] + red[3];
        clsn[(size_t)b * 256 + t] = x / fmaxf(sqrtf(tot), 1e-12f);
    }
}

// ---------------------------------------------------------------------------
// kvf_k: fused tokens->f16 + K-proj + V-proj. grid 256 x 512 threads.
// ---------------------------------------------------------------------------
__global__ __launch_bounds__(512, 2) void kvf_k(
    const float* __restrict__ tokens,
    const _Float16* __restrict__ wkT, const _Float16* __restrict__ wvT,
    const float* __restrict__ bk, const float* __restrict__ bv,
    _Float16* __restrict__ kT, _Float16* __restrict__ vT)
{
    __shared__ __align__(16) _Float16 Sb[2][8192];   // 2 x 16KB: 32 rows x 256d tiled

    const int t = threadIdx.x, lane = t & 63, w = t >> 6;
    const int l15 = lane & 15, quad = lane >> 4;
    const int lofs = l15 * 32 + quad * 8;
    const int lofsA = ((l15 * 4 + quad) ^ ((l15 >> 1) & 7)) * 8;
    const int bx = blockIdx.x;
    const int b = bx & 31, chunk = bx >> 5;

    f16x8 wk[2][8], wv[2][8];
#pragma unroll
    for (int j = 0; j < 2; j++)
#pragma unroll
        for (int ks = 0; ks < 8; ks++) {
            wk[j][ks] = *(const f16x8*)(wkT + ((size_t)(2 * w + j) * 8 + ks) * 512 + lofs);
            wv[j][ks] = *(const f16x8*)(wvT + ((size_t)(2 * w + j) * 8 + ks) * 512 + lofs);
        }
    f32x4 bi0 = *(const f32x4*)(bk + w * 32 + quad * 4);
    f32x4 bi1 = *(const f32x4*)(bk + w * 32 + 16 + quad * 4);
    const float bv0 = bv[(2 * w) * 16 + l15];
    const float bv1 = bv[(2 * w + 1) * 16 + l15];

    const int rr = t >> 5, d8 = t & 31;
    const float* tbase = tokens + ((size_t)b * 2048 + chunk * 256) * 256 + rr * 256 + d8 * 8;
    const int mskW = ((rr >> 1) & 7) ^ (((d8 >> 2) & 3) << 1);
    const int wofs0 = (d8 >> 2) * 512 + (((rr * 4 + (d8 & 3)) ^ mskW) * 8);
    const int wofs1 = wofs0 + 8 * 512;

    float4 pa0, pa1, pb0, pb1;

#define KVF_LOADS(P) do {                                                    \
        const float* sp_ = tbase + (size_t)(P) * 8192;                       \
        pa0 = *(const float4*)(sp_);                                         \
        pa1 = *(const float4*)(sp_ + 4);                                     \
        pb0 = *(const float4*)(sp_ + 4096);                                  \
        pb1 = *(const float4*)(sp_ + 4100);                                  \
    } while (0)

#define KVF_STAGE(BUF) do {                                                  \
        f16x8 h0, h1;                                                        \
        h0[0] = (_Float16)pa0.x; h0[1] = (_Float16)pa0.y;                    \
        h0[2] = (_Float16)pa0.z; h0[3] = (_Float16)pa0.w;                    \
        h0[4] = (_Float16)pa1.x; h0[5] = (_Float16)pa1.y;                    \
        h0[6] = (_Float16)pa1.z; h0[7] = (_Float16)pa1.w;                    \
        h1[0] = (_Float16)pb0.x; h1[1] = (_Float16)pb0.y;                    \
        h1[2] = (_Float16)pb0.z; h1[3] = (_Float16)pb0.w;                    \
        h1[4] = (_Float16)pb1.x; h1[5] = (_Float16)pb1.y;                    \
        h1[6] = (_Float16)pb1.z; h1[7] = (_Float16)pb1.w;                    \
        *(f16x8*)((BUF) + wofs0) = h0;                                       \
        *(f16x8*)((BUF) + wofs1) = h1;                                       \
    } while (0)

    KVF_LOADS(0);
    KVF_STAGE(&Sb[0][0]);
    LGKM_BAR();

    for (int p = 0; p < 8; p++) {
        if (p < 7) KVF_LOADS(p + 1);
        __builtin_amdgcn_sched_barrier(0);

        const _Float16* lb = &Sb[p & 1][0];
        const int stg0 = chunk * 16 + p * 2;
        const int sp = chunk * 8 + p;

        f16x8 a[2][8];
#pragma unroll
        for (int st = 0; st < 2; st++)
#pragma unroll
            for (int ks = 0; ks < 8; ks++)
                a[st][ks] = *(const f16x8*)(lb + (st * 8 + ks) * 512 + (lofsA ^ ((ks & 3) * 16)));

        // K: c[row=dim][col=seq]
#pragma unroll
        for (int st = 0; st < 2; st++) {
            f32x4 c0 = {0.f, 0.f, 0.f, 0.f}, c1 = {0.f, 0.f, 0.f, 0.f};
#pragma unroll
            for (int ks = 0; ks < 8; ks++) {
                c0 = MFMA16(wk[0][ks], a[st][ks], c0);
                c1 = MFMA16(wk[1][ks], a[st][ks], c1);
            }
            f16x4 p0, p1;
#pragma unroll
            for (int reg = 0; reg < 4; reg++) {
                p0[reg] = (_Float16)(c0[reg] + bi0[reg]);
                p1[reg] = (_Float16)(c1[reg] + bi1[reg]);
            }
            _Float16* tp = kT + ((size_t)(b * 128 + stg0 + st) * 8 + w) * 512 + l15 * 32;
            *(f16x4*)(tp + (quad >> 1) * 8 + (quad & 1) * 4) = p0;
            *(f16x4*)(tp + (2 + (quad >> 1)) * 8 + (quad & 1) * 4) = p1;
        }

        // V: c[row=seq][col=dim]
#pragma unroll
        for (int j = 0; j < 2; j++) {
            f32x4 c0 = {0.f, 0.f, 0.f, 0.f}, c1 = {0.f, 0.f, 0.f, 0.f};
#pragma unroll
            for (int ks = 0; ks < 8; ks++) {
                c0 = MFMA16(a[0][ks], wv[j][ks], c0);
                c1 = MFMA16(a[1][ks], wv[j][ks], c1);
            }
            const float bb = j ? bv1 : bv0;
            f16x4 p0, p1;
#pragma unroll
            for (int reg = 0; reg < 4; reg++) {
                p0[reg] = (_Float16)(c0[reg] + bb);
                p1[reg] = (_Float16)(c1[reg] + bb);
            }
            _Float16* tp = vT + ((size_t)(b * 16 + 2 * w + j) * 64 + sp) * 512 + l15 * 32;
            *(f16x4*)(tp + (quad >> 1) * 8 + (quad & 1) * 4) = p0;
            *(f16x4*)(tp + (2 + (quad >> 1)) * 8 + (quad & 1) * 4) = p1;
        }

        if (p < 7) {
            KVF_STAGE(&Sb[(p + 1) & 1][0]);
            LGKM_BAR();
        }
    }
#undef KVF_LOADS
#undef KVF_STAGE
}

// ---------------------------------------------------------------------------
// slotq_k: fused slots-init + qslot. grid 1024 x 256: block = one row-tile
// (16 rows). slots = mu + eps*sigma -> LDS(swz) + f32 global; then
// qsT = (slots@Wqs + qint2)/16 tiled.
// ---------------------------------------------------------------------------
__global__ __launch_bounds__(256, 4) void slotq_k(
    const float* __restrict__ noise, const float* __restrict__ slot_mu,
    const float* __restrict__ slot_sigma,
    const _Float16* __restrict__ wqsT, const float* __restrict__ qint2,
    float* __restrict__ slots, _Float16* __restrict__ qsT)
{
    __shared__ float sb[16 * 256];
    const int tid = threadIdx.x, lane = tid & 63, w4 = tid >> 6;
    const int l15 = lane & 15, quad = lane >> 4;
    const int lofs = l15 * 32 + quad * 8;
    const int rt = blockIdx.x;
    const int gr0 = rt * 16;

    {
        const int lr = w4 * 4 + quad;
        const int gr = gr0 + lr;
        const int b = gr >> 9, i = (gr >> 2) & 127, n = gr & 3;
        const float* np = noise + (((size_t)i * BSZ + b) * 4 + n) * 256;
#pragma unroll
        for (int k = 0; k < 4; k++) {
            const int c = k * 64 + l15 * 4;
            float4 mu = *(const float4*)(slot_mu + n * 256 + c);
            float4 sg = *(const float4*)(slot_sigma + n * 256 + c);
            float4 ns = *(const float4*)(np + c);
            float4 o;
            o.x = mu.x + ns.x * sg.x; o.y = mu.y + ns.y * sg.y;
            o.z = mu.z + ns.z * sg.z; o.w = mu.w + ns.w * sg.w;
            *slp(sb, lr, c) = o;
            *(float4*)(slots + (size_t)gr * 256 + c) = o;
        }
    }
    __syncthreads();

    f16x8 bs[8];
#pragma unroll
    for (int ks = 0; ks < 8; ks++) {
        const int c0 = ks * 32 + quad * 8;
        float4 xa = *slp(sb, l15, c0);
        float4 xb = *slp(sb, l15, c0 + 4);
        bs[ks][0] = (_Float16)xa.x; bs[ks][1] = (_Float16)xa.y;
        bs[ks][2] = (_Float16)xa.z; bs[ks][3] = (_Float16)xa.w;
        bs[ks][4] = (_Float16)xb.x; bs[ks][5] = (_Float16)xb.y;
        bs[ks][6] = (_Float16)xb.z; bs[ks][7] = (_Float16)xb.w;
    }
    const int iq = ((gr0 + l15) & 511) >> 2;
#pragma unroll
    for (int d = 0; d < 4; d++) {
        const int dti = w4 * 4 + d;
        f32x4 c = {0.f, 0.f, 0.f, 0.f};
#pragma unroll
        for (int ks = 0; ks < 8; ks++)
            c = MFMA16(*(const f16x8*)(wqsT + ((size_t)dti * 8 + ks) * 512 + lofs), bs[ks], c);
        float4 qi = *(const float4*)(qint2 + (size_t)iq * 256 + dti * 16 + quad * 4);
        f16x4 o;
#pragma unroll
        for (int reg = 0; reg < 4; reg++) o[reg] = (_Float16)((c[reg] + qi[reg]) * 0.0625f);
        *(f16x4*)(qsT + ((size_t)rt * 8 + (dti >> 1)) * 512 + l15 * 32
                  + ((dti & 1) * 2 + (quad >> 1)) * 8 + (quad & 1) * 4) = o;
    }
}

// ---------------------------------------------------------------------------
// attn_k: LDS-staged, pipelined, 2 blocks/CU. grid 512 x 512 threads:
// b = bx&31, rb = (bx>>5)&3 (128-row group), sk = bx>>7 (512-key chunk).
// 16 rows/wave (O = 64 VGPR), 32-key substeps x16, K dbuf + V single buf.
// LDS 58KB -> 2 blocks/CU; __launch_bounds__(512,4) pins VGPR <= 128.
// Accumulation chains identical to the r5 attn -> bitwise-same Opart/psum4.
// ---------------------------------------------------------------------------
__global__ __launch_bounds__(512, 4) void attn_k(
    const _Float16* __restrict__ qsT, const _Float16* __restrict__ kT,
    const _Float16* __restrict__ vT,
    _Float16* __restrict__ Opart, float* __restrict__ psum4)
{
    __shared__ __align__(16) _Float16 arena[24576];  // Kb[2][8192] | Vb[8192], 48KB
    __shared__ __align__(16) _Float16 pb[8][640];    // per-wave P: 16 x 40, 10KB

    _Float16* KbA = arena;              // 2 x 8192 halves (32 keys x 256d each)
    _Float16* VbA = arena + 16384;      // 8192 halves (16 d-tiles x 32 keys)

    const int tid = threadIdx.x, lane = tid & 63, wv = tid >> 6;
    const int l15 = lane & 15, quad = lane >> 4;
    const int lofs = l15 * 32 + quad * 8;
    const int lofsA = ((l15 * 4 + quad) ^ ((l15 >> 1) & 7)) * 8;
    const int lnsw = (lane ^ ((lane >> 3) & 7)) * 8;
    const int bx = blockIdx.x;
    const int b = bx & 31, rb = (bx >> 5) & 3, sk = bx >> 7;
    const int gr0 = b * 512 + rb * 128 + wv * 16;
    const int rt_q = gr0 >> 4;

    _Float16* pw = pb[wv];

    const _Float16* kSrc = kT + ((size_t)(b * 128 + sk * 32) * 8) * 512;
    const _Float16* vSrc = vT + ((size_t)(b * 16) * 64 + sk * 16) * 512;

    // prologue: K(0) — 16 x 1KB tiles, 2 per wave
#pragma unroll
    for (int j = 0; j < 2; j++) {
        const int ee = wv * 2 + j;
        GLL(kSrc + (size_t)((ee >> 3) * 8 + (ee & 7)) * 512 + lnsw,
            KbA + ee * 512 + lane * 8);
    }

    f16x8 q[8];
#pragma unroll
    for (int ks = 0; ks < 8; ks++)
        q[ks] = *(const f16x8*)(qsT + ((size_t)rt_q * 8 + ks) * 512 + lofs);

    f32x4 O[16];
#pragma unroll
    for (int dt = 0; dt < 16; dt++) O[dt] = (f32x4){0.f, 0.f, 0.f, 0.f};
    float ps[4] = {0.f, 0.f, 0.f, 0.f};

    asm volatile("s_waitcnt vmcnt(0)" ::: "memory");
    __builtin_amdgcn_s_barrier();
    __builtin_amdgcn_sched_barrier(0);

    for (int ss = 0; ss < 16; ss++) {
        const int cur = ss & 1;

        // stage V(ss): 16 d-tiles of 32 keys
#pragma unroll
        for (int j = 0; j < 2; j++) {
            const int ee = wv * 2 + j;
            GLL(vSrc + (size_t)(ee * 64 + ss) * 512 + lnsw, VbA + ee * 512 + lane * 8);
        }
        if (ss < 15) {
#pragma unroll
            for (int j = 0; j < 2; j++) {
                const int ee = wv * 2 + j;
                GLL(kSrc + (size_t)((2 * (ss + 1) + (ee >> 3)) * 8 + (ee & 7)) * 512 + lnsw,
                    KbA + (cur ^ 1) * 8192 + ee * 512 + lane * 8);
            }
            // outstanding: [K(ss)<=2][V(ss)=2][K(ss+1)=2] -> wait K(ss)
            asm volatile("s_waitcnt vmcnt(4)" ::: "memory");
        } else {
            asm volatile("s_waitcnt vmcnt(2)" ::: "memory");
        }
        __builtin_amdgcn_s_barrier();
        __builtin_amdgcn_sched_barrier(0);

        // QK: 2 key-16-tiles; same kt/ks/exp order as r5
#pragma unroll
        for (int kt = 0; kt < 2; kt++) {
            const _Float16* kp = KbA + cur * 8192 + (kt * 8) * 512;
            f32x4 c0 = {0.f, 0.f, 0.f, 0.f};
#pragma unroll
            for (int ks = 0; ks < 8; ks++)
                c0 = MFMA16(q[ks], *(const f16x8*)(kp + ks * 512 + lofsA), c0);
            const int col = kt * 16 + l15;
#pragma unroll
            for (int reg = 0; reg < 4; reg++) {
                float p0 = __expf(fminf(c0[reg], 10.5f));
                ps[reg] += p0;
                pw[(quad * 4 + reg) * 40 + col] = (_Float16)p0;
            }
        }

        __builtin_amdgcn_sched_barrier(0);
        asm volatile("s_waitcnt lgkmcnt(0)" ::: "memory");   // own-wave P visible
        if (ss < 15) {
            asm volatile("s_waitcnt vmcnt(2)" ::: "memory"); // V landed, K flying
        } else {
            asm volatile("s_waitcnt vmcnt(0)" ::: "memory");
        }
        __builtin_amdgcn_s_barrier();
        __builtin_amdgcn_sched_barrier(0);

        // PV: 16 dim-tiles over the 32 staged keys (same chain order as r5)
        {
            f16x8 pa = *(const f16x8*)(pw + l15 * 40 + quad * 8);
#pragma unroll
            for (int dt = 0; dt < 16; dt++)
                O[dt] = MFMA16(pa, *(const f16x8*)(VbA + dt * 512 + lofsA), O[dt]);
        }
        __builtin_amdgcn_sched_barrier(0);
        __builtin_amdgcn_s_barrier();
        __builtin_amdgcn_sched_barrier(0);
    }

    // psum reduce over l15 (key) axis
#pragma unroll
    for (int msk = 1; msk <= 8; msk <<= 1)
#pragma unroll
        for (int reg = 0; reg < 4; reg++) ps[reg] += __shfl_xor(ps[reg], msk, 64);
    if (l15 == 0) {
#pragma unroll
        for (int reg = 0; reg < 4; reg++)
            psum4[(size_t)sk * 16384 + gr0 + quad * 4 + reg] = ps[reg];
    }

    // O transpose via per-wave scratch in the (now dead) K/V arena
    _Float16* ow = arena + wv * 2176;   // 16 x 136 halves per wave (34KB < 48KB)
#pragma unroll
    for (int hd = 0; hd < 2; hd++) {
#pragma unroll
        for (int dt = 0; dt < 8; dt++) {
            const int dti = hd * 8 + dt;
#pragma unroll
            for (int reg = 0; reg < 4; reg++)
                ow[(quad * 4 + reg) * 136 + dt * 16 + l15] = (_Float16)O[dti][reg];
        }
#pragma unroll
        for (int p2 = 0; p2 < 4; p2++) {
            const int u = lane + p2 * 64;
            const int row = u >> 4, col8 = u & 15;
            *(f16x8*)(Opart + ((size_t)sk * 16384 + gr0 + row) * 256 + hd * 128 + col8 * 8) =
                *(const f16x8*)(ow + row * 136 + col8 * 8);
        }
    }
}

// ---------------------------------------------------------------------------
// mlp_k: fused LN1+LN2+FFN1+FFN2 (+qslot | final). grid 1024 x 256 threads.
// Block owns 16 rows (one row-tile): b = bx&31, rg = bx>>5 (0..31).
// ---------------------------------------------------------------------------
__global__ __launch_bounds__(256, 4) void mlp_k(
    const _Float16* __restrict__ Opart, const float* __restrict__ psum4,
    float* __restrict__ slots,
    const float* __restrict__ ln1_g, const float* __restrict__ ln1_b,
    const float* __restrict__ ln2_g, const float* __restrict__ ln2_b,
    const _Float16* __restrict__ wf1T, const float* __restrict__ bf1,
    const _Float16* __restrict__ wf2T, const float* __restrict__ bf2,
    const _Float16* __restrict__ wqsT, const float* __restrict__ qint2,
    _Float16* __restrict__ qsT,
    const float* __restrict__ qn, const float* __restrict__ clsn,
    const float* __restrict__ alphap, const float* __restrict__ tempp,
    float* __restrict__ out, int it)
{
    __shared__ float sl[16 * 256];                 // 16KB swizzled x1/slots
    __shared__ float2 st2[16];                     // LN2 stats per row
    __shared__ __align__(16) _Float16 actL[8192];  // 16KB act tiled (swizzled)

    const int tid = threadIdx.x, lane = tid & 63, w4 = tid >> 6;
    const int l15 = lane & 15, quad = lane >> 4;
    const int lofs = l15 * 32 + quad * 8;
    const int lofsA = ((l15 * 4 + quad) ^ ((l15 >> 1) & 7)) * 8;
    const int bx = blockIdx.x;
    const int b = bx & 31, rg = bx >> 5;
    const int R0 = b * 512 + rg * 16;

    // ---- phase 1: y = slots + O/psum; x1 = LN1(y) -> sl; LN2 stats -> st2
    {
        const int lr = w4 * 4 + quad;
        const int gr = R0 + lr;
        float l = 0.f;
#pragma unroll
        for (int j = 0; j < 4; j++) l += psum4[(size_t)j * 16384 + gr];
        const float invl = 1.f / l;
        float4 y[4];
        float sm = 0.f, sq = 0.f;
#pragma unroll
        for (int k = 0; k < 4; k++) {
            const int c = k * 64 + l15 * 4;
            float4 o4 = {0.f, 0.f, 0.f, 0.f};
#pragma unroll
            for (int j = 0; j < 4; j++) {
                f16x4 p = *(const f16x4*)(Opart + ((size_t)j * 16384 + gr) * 256 + c);
                o4.x += (float)p[0]; o4.y += (float)p[1];
                o4.z += (float)p[2]; o4.w += (float)p[3];
            }
            float4 s4 = *(const float4*)(slots + (size_t)gr * 256 + c);
            y[k].x = s4.x + o4.x * invl; y[k].y = s4.y + o4.y * invl;
            y[k].z = s4.z + o4.z * invl; y[k].w = s4.w + o4.w * invl;
            sm += y[k].x + y[k].y + y[k].z + y[k].w;
            sq += dot4f(y[k], y[k]);
        }
#pragma unroll
        for (int m = 1; m <= 8; m <<= 1) { sm += __shfl_xor(sm, m, 64); sq += __shfl_xor(sq, m, 64); }
        const float mean = sm * (1.f / 256.f);
        const float rstd = rsqrtf(sq * (1.f / 256.f) - mean * mean + 1e-5f);
        float sm2 = 0.f, sq2 = 0.f;
#pragma unroll
        for (int k = 0; k < 4; k++) {
            const int c = k * 64 + l15 * 4;
            float4 g1 = *(const float4*)(ln1_g + c);
            float4 b1 = *(const float4*)(ln1_b + c);
            float4 x1;
            x1.x = (y[k].x - mean) * rstd * g1.x + b1.x;
            x1.y = (y[k].y - mean) * rstd * g1.y + b1.y;
            x1.z = (y[k].z - mean) * rstd * g1.z + b1.z;
            x1.w = (y[k].w - mean) * rstd * g1.w + b1.w;
            *slp(sl, lr, c) = x1;
            sm2 += x1.x + x1.y + x1.z + x1.w;
            sq2 += dot4f(x1, x1);
        }
#pragma unroll
        for (int m = 1; m <= 8; m <<= 1) { sm2 += __shfl_xor(sm2, m, 64); sq2 += __shfl_xor(sq2, m, 64); }
        const float mean2 = sm2 * (1.f / 256.f);
        const float rstd2 = rsqrtf(sq2 * (1.f / 256.f) - mean2 * mean2 + 1e-5f);
        if (l15 == 0) st2[lr] = make_float2(mean2, rstd2);
    }
    __syncthreads();

    // ---- phase 2: act = gelu(LN2(x1)@Wf1+bf1); wave w4 owns htis w4*8..+7
    {
        const float2 s2 = st2[l15];
        f16x8 bh[8];
#pragma unroll
        for (int ks = 0; ks < 8; ks++) {
            const int c0 = ks * 32 + quad * 8;
            float4 xa = *slp(sl, l15, c0);
            float4 xb = *slp(sl, l15, c0 + 4);
            float4 ga = *(const float4*)(ln2_g + c0);
            float4 gb = *(const float4*)(ln2_g + c0 + 4);
            float4 ba = *(const float4*)(ln2_b + c0);
            float4 bb2 = *(const float4*)(ln2_b + c0 + 4);
            bh[ks][0] = (_Float16)((xa.x - s2.x) * s2.y * ga.x + ba.x);
            bh[ks][1] = (_Float16)((xa.y - s2.x) * s2.y * ga.y + ba.y);
            bh[ks][2] = (_Float16)((xa.z - s2.x) * s2.y * ga.z + ba.z);
            bh[ks][3] = (_Float16)((xa.w - s2.x) * s2.y * ga.w + ba.w);
            bh[ks][4] = (_Float16)((xb.x - s2.x) * s2.y * gb.x + bb2.x);
            bh[ks][5] = (_Float16)((xb.y - s2.x) * s2.y * gb.y + bb2.y);
            bh[ks][6] = (_Float16)((xb.z - s2.x) * s2.y * gb.z + bb2.z);
            bh[ks][7] = (_Float16)((xb.w - s2.x) * s2.y * gb.w + bb2.w);
        }
#pragma unroll 2
        for (int t8 = 0; t8 < 8; t8++) {
            const int hti = w4 * 8 + t8;
            f32x4 c = {0.f, 0.f, 0.f, 0.f};
#pragma unroll
            for (int ks = 0; ks < 8; ks++)
                c = MFMA16(*(const f16x8*)(wf1T + ((size_t)hti * 8 + ks) * 512 + lofs), bh[ks], c);
            float4 bb = *(const float4*)(bf1 + hti * 16 + quad * 4);
            f16x4 o;
#pragma unroll
            for (int reg = 0; reg < 4; reg++) {
                float xg = c[reg] + bb[reg];
                o[reg] = (_Float16)(0.5f * xg * (1.f + erff(xg * 0.70710678118654752f)));
            }
            const int gA = l15 * 4 + (hti & 1) * 2 + (quad >> 1);
            *(f16x4*)(actL + ((size_t)(hti >> 1)) * 512
                      + ((gA ^ ((l15 >> 1) & 7)) * 8) + (quad & 1) * 4) = o;
        }
    }
    __syncthreads();

    // ---- phase 3: slots_new = x1 + act@Wf2 + bf2 -> sl
    {
        f32x4 c[4];
#pragma unroll
        for (int d = 0; d < 4; d++) {
            const int dti = w4 * 4 + d;
            float4 x4 = *slp(sl, l15, dti * 16 + quad * 4);
            float4 bb = *(const float4*)(bf2 + dti * 16 + quad * 4);
            c[d] = (f32x4){x4.x + bb.x, x4.y + bb.y, x4.z + bb.z, x4.w + bb.w};
        }
        for (int ks = 0; ks < 16; ks++) {
            f16x8 afrag = *(const f16x8*)(actL + (size_t)ks * 512 + lofsA);
#pragma unroll
            for (int d = 0; d < 4; d++)
                c[d] = MFMA16(*(const f16x8*)(wf2T + ((size_t)(w4 * 4 + d) * 16 + ks) * 512 + lofs),
                              afrag, c[d]);
        }
        __syncthreads();
#pragma unroll
        for (int d = 0; d < 4; d++) {
            const int dti = w4 * 4 + d;
            float4 v = {c[d][0], c[d][1], c[d][2], c[d][3]};
            *slp(sl, l15, dti * 16 + quad * 4) = v;
        }
    }
    __syncthreads();

    if (it < 2) {
        // ---- phase 4a: qsT for next iteration
        f16x8 bs[8];
#pragma unroll
        for (int ks = 0; ks < 8; ks++) {
            const int c0 = ks * 32 + quad * 8;
            float4 xa = *slp(sl, l15, c0);
            float4 xb = *slp(sl, l15, c0 + 4);
            bs[ks][0] = (_Float16)xa.x; bs[ks][1] = (_Float16)xa.y;
            bs[ks][2] = (_Float16)xa.z; bs[ks][3] = (_Float16)xa.w;
            bs[ks][4] = (_Float16)xb.x; bs[ks][5] = (_Float16)xb.y;
            bs[ks][6] = (_Float16)xb.z; bs[ks][7] = (_Float16)xb.w;
        }
        const int iq = rg * 4 + (l15 >> 2);
        const int rtg = b * 32 + rg;
#pragma unroll
        for (int d = 0; d < 4; d++) {
            const int dti = w4 * 4 + d;
            f32x4 c = {0.f, 0.f, 0.f, 0.f};
#pragma unroll
            for (int ks = 0; ks < 8; ks++)
                c = MFMA16(*(const f16x8*)(wqsT + ((size_t)dti * 8 + ks) * 512 + lofs), bs[ks], c);
            float4 qi = *(const float4*)(qint2 + (size_t)iq * 256 + dti * 16 + quad * 4);
            f16x4 o;
#pragma unroll
            for (int reg = 0; reg < 4; reg++) o[reg] = (_Float16)((c[reg] + qi[reg]) * 0.0625f);
            *(f16x4*)(qsT + ((size_t)rtg * 8 + (dti >> 1)) * 512 + l15 * 32
                      + ((dti & 1) * 2 + (quad >> 1)) * 8 + (quad & 1) * 4) = o;
        }
        // ---- phase 4b: slots_new -> global (coalesced)
        {
            const int lr2 = tid >> 4, c16 = tid & 15;
#pragma unroll
            for (int q4 = 0; q4 < 4; q4++) {
                float4 v = *slp(sl, lr2, c16 * 16 + q4 * 4);
                *(float4*)(slots + (size_t)(R0 + lr2) * 256 + c16 * 16 + q4 * 4) = v;
            }
        }
    } else {
        // ---- phase 4c: final scoring (1 intent per wave, 4 per block)
        const int i = rg * 4 + w4;
        float4 qv = *(const float4*)(qn + (size_t)i * 256 + lane * 4);
        float4 xs[4];
        float st4[4];
#pragma unroll
        for (int n = 0; n < 4; n++) {
            xs[n] = *slp(sl, w4 * 4 + n, lane * 4);
            float ss = dot4f(xs[n], xs[n]);
            float sq = dot4f(xs[n], qv);
#pragma unroll
            for (int m = 1; m < 64; m <<= 1) { ss += __shfl_xor(ss, m, 64); sq += __shfl_xor(sq, m, 64); }
            st4[n] = sq / fmaxf(sqrtf(ss), 1e-12f);
        }
        float mx = fmaxf(fmaxf(st4[0], st4[1]), fmaxf(st4[2], st4[3]));
        float e0 = __expf(st4[0] - mx), e1 = __expf(st4[1] - mx);
        float e2 = __expf(st4[2] - mx), e3 = __expf(st4[3] - mx);
        float inv = 1.f / (e0 + e1 + e2 + e3);
        float4 smv;
        smv.x = (e0 * xs[0].x + e1 * xs[1].x + e2 * xs[2].x + e3 * xs[3].x) * inv;
        smv.y = (e0 * xs[0].y + e1 * xs[1].y + e2 * xs[2].y + e3 * xs[3].y) * inv;
        smv.z = (e0 * xs[0].z + e1 * xs[1].z + e2 * xs[2].z + e3 * xs[3].z) * inv;
        smv.w = (e0 * xs[0].w + e1 * xs[1].w + e2 * xs[2].w + e3 * xs[3].w) * inv;
        float ssm = dot4f(smv, smv);
        float sqn = dot4f(smv, qv);
        float4 cv = *(const float4*)(clsn + (size_t)b * 256 + lane * 4);
        float cq = dot4f(cv, qv);
#pragma unroll
        for (int m = 1; m < 64; m <<= 1) {
            ssm += __shfl_xor(ssm, m, 64);
            sqn += __shfl_xor(sqn, m, 64);
            cq  += __shfl_xor(cq,  m, 64);
        }
        if (lane == 0) {
            float score = cq + alphap[0] * sqn / fmaxf(sqrtf(ssm), 1e-12f);
            out[(size_t)b * NI + i] = score / fmaxf(tempp[0], 1e-4f);
        }
    }
}

// ---------------------------------------------------------------------------
extern "C" void kernel_launch(void* const* d_in, const int* in_sizes, int n_in,
                              void* d_out, int out_size, void* d_ws, size_t ws_size,
                              hipStream_t stream)
{
    const float* tokens     = (const float*)d_in[0];
    const float* cls_embed  = (const float*)d_in[1];
    const float* intent_q   = (const float*)d_in[2];
    const float* noise      = (const float*)d_in[3];
    const float* Wk  = (const float*)d_in[4];
    const float* bk  = (const float*)d_in[5];
    const float* Wv  = (const float*)d_in[6];
    const float* bv  = (const float*)d_in[7];
    const float* Wqs = (const float*)d_in[8];
    const float* bqs = (const float*)d_in[9];
    const float* Wqi = (const float*)d_in[10];
    const float* bqi = (const float*)d_in[11];
    const float* ln1g = (const float*)d_in[12];
    const float* ln1b = (const float*)d_in[13];
    const float* ln2g = (const float*)d_in[14];
    const float* ln2b = (const float*)d_in[15];
    const float* Wf1 = (const float*)d_in[16];
    const float* bf1 = (const float*)d_in[17];
    const float* Wf2 = (const float*)d_in[18];
    const float* bf2 = (const float*)d_in[19];
    const float* slot_mu    = (const float*)d_in[20];
    const float* slot_sigma = (const float*)d_in[21];
    const float* alphap = (const float*)d_in[22];
    const float* tempp  = (const float*)d_in[23];
    float* out = (float*)d_out;

    char* base = (char*)d_ws;
    _Float16* qsT   = (_Float16*)(base);                        //  8388608 B
    _Float16* kT    = (_Float16*)(base + 33554432u);            // 33554432 B
    _Float16* vT    = (_Float16*)(base + 67108864u);            // 33554432 B
    _Float16* Opart = (_Float16*)(base + 100663296u);           // 33554432 B
    float* slots    = (float*)(base + 134217728u);              // 16777216 B
    _Float16* wkT   = (_Float16*)(base + 150994944u);           //   131072 B
    _Float16* wvT   = (_Float16*)(base + 151126016u);
    _Float16* wqsT  = (_Float16*)(base + 151257088u);
    _Float16* wf1T  = (_Float16*)(base + 151388160u);           //   262144 B
    _Float16* wf2T  = (_Float16*)(base + 151650304u);           //   262144 B
    float* qint2    = (float*)(base + 151912448u);              //   131072 B
    float* qnb      = (float*)(base + 152043520u);              //   131072 B
    float* clsn     = (float*)(base + 152174592u);              //    32768 B
    float* psum4    = (float*)(base + 152207360u);              //   262144 B

    prep<<<272, 256, 0, stream>>>(Wk, Wv, Wqs, Wf1, Wf2, intent_q, Wqi, bqi, bqs,
                                  cls_embed, wkT, wvT, wqsT, wf1T, wf2T,
                                  qint2, qnb, clsn);
    kvf_k<<<256, 512, 0, stream>>>(tokens, wkT, wvT, bk, bv, kT, vT);
    slotq_k<<<1024, 256, 0, stream>>>(noise, slot_mu, slot_sigma, wqsT, qint2,
                                      slots, qsT);

    for (int it = 0; it < 3; it++) {
        attn_k<<<512, 512, 0, stream>>>(qsT, kT, vT, Opart, psum4);
        mlp_k<<<1024, 256, 0, stream>>>(Opart, psum4, slots,
                                        ln1g, ln1b, ln2g, ln2b,
                                        wf1T, bf1, wf2T, bf2,
                                        wqsT, qint2, qsT,
                                        qnb, clsn, alphap, tempp, out, it);
    }
}

// Round 8
// 438.062 us; speedup vs baseline: 1.9259x; 1.1169x over previous
//
#include <hip/hip_runtime.h>
#include <math.h>

#define BSZ 32
#define NI  128

typedef __attribute__((ext_vector_type(8))) _Float16 f16x8;
typedef __attribute__((ext_vector_type(4))) _Float16 f16x4;
typedef __attribute__((ext_vector_type(4))) float    f32x4;

// MFMA16(X, Y, C): C[row = quad*4+reg <- X's l15][col = l15 <- Y's l15]
// X,Y k-index = quad*8 + j.
// Tiled operand format: 1KB tiles, inner l15*32 + quad*8 + j for a fragment.
#define MFMA16(a, b, c) __builtin_amdgcn_mfma_f32_16x16x32_f16((a), (b), (c), 0, 0, 0)

// global -> LDS async DMA, 16B per lane, wave-linear dest
#define GLL(g, l) __builtin_amdgcn_global_load_lds(                          \
    (const __attribute__((address_space(1))) void*)(g),                      \
    (__attribute__((address_space(3))) void*)(l), 16, 0, 0)

// barrier that waits LDS ops only (leaves global loads/stores in flight)
#define LGKM_BAR() do {                                                      \
    asm volatile("s_waitcnt lgkmcnt(0)" ::: "memory");                       \
    __builtin_amdgcn_sched_barrier(0);                                       \
    __builtin_amdgcn_s_barrier();                                            \
    __builtin_amdgcn_sched_barrier(0); } while (0)

__device__ inline float dot4f(float4 a, float4 b) {
    return a.x * b.x + a.y * b.y + a.z * b.z + a.w * b.w;
}

// swizzled pointer into row-major f32 LDS: row r, col c (multiple of 4).
__device__ inline float4* slp(float* base, int r, int c) {
    return (float4*)(base + r * 256 + ((((c) >> 2) ^ (r & 7)) << 2));
}

// ---------------------------------------------------------------------------
// 64x64 f32->f16 transpose tile -> TILED output (element (n,k) from src[k][n])
// ---------------------------------------------------------------------------
__device__ inline void tpose64(const float* __restrict__ src, int Csrc,
                               _Float16* __restrict__ dstT, int KT,
                               int r0, int c0, _Float16 (*tbuf)[72], int tid)
{
#pragma unroll
    for (int it = 0; it < 4; it++) {
        int idx = tid + it * 256;
        int rr = idx >> 4, c4 = idx & 15;
        float4 w = *(const float4*)(src + (size_t)(r0 + rr) * Csrc + c0 + c4 * 4);
        tbuf[c4 * 4 + 0][rr] = (_Float16)w.x;
        tbuf[c4 * 4 + 1][rr] = (_Float16)w.y;
        tbuf[c4 * 4 + 2][rr] = (_Float16)w.z;
        tbuf[c4 * 4 + 3][rr] = (_Float16)w.w;
    }
    __syncthreads();
#pragma unroll
    for (int it = 0; it < 2; it++) {
        int idx = tid + it * 256;
        int orr = idx >> 3, oc8 = idx & 7;
        int n = c0 + orr;
        size_t tile = (size_t)(n >> 4) * KT + (r0 >> 5) + (oc8 >> 2);
        *(f16x8*)(dstT + tile * 512 + (n & 15) * 32 + (oc8 & 3) * 8) = *(const f16x8*)&tbuf[orr][oc8 * 8];
    }
}

// ---------------------------------------------------------------------------
// prep: tiled f16 weights, qn, cls_n, qint2 = q@Wqi + bqi + bqs
// ---------------------------------------------------------------------------
__global__ __launch_bounds__(256) void prep(
    const float* __restrict__ Wk, const float* __restrict__ Wv,
    const float* __restrict__ Wqs, const float* __restrict__ Wf1,
    const float* __restrict__ Wf2,
    const float* __restrict__ intent_q, const float* __restrict__ Wqi,
    const float* __restrict__ bqi, const float* __restrict__ bqs,
    const float* __restrict__ cls_embed,
    _Float16* __restrict__ wkT, _Float16* __restrict__ wvT,
    _Float16* __restrict__ wqsT, _Float16* __restrict__ wf1T,
    _Float16* __restrict__ wf2T,
    float* __restrict__ qint2, float* __restrict__ qn, float* __restrict__ clsn)
{
    __shared__ _Float16 tbuf[64][72];
    __shared__ float buf[256];
    __shared__ float red[4];
    const int t = threadIdx.x, blk = blockIdx.x;
    const int lane = t & 63, w = t >> 6;

    if (blk < 112) {
        if (blk < 16)       tpose64(Wk, 256, wkT, 8, (blk >> 2) * 64, (blk & 3) * 64, tbuf, t);
        else if (blk < 32)  { int tt = blk - 16; tpose64(Wv, 256, wvT, 8, (tt >> 2) * 64, (tt & 3) * 64, tbuf, t); }
        else if (blk < 48)  { int tt = blk - 32; tpose64(Wqs, 256, wqsT, 8, (tt >> 2) * 64, (tt & 3) * 64, tbuf, t); }
        else if (blk < 80)  { int tt = blk - 48; tpose64(Wf1, 512, wf1T, 8, (tt & 3) * 64, (tt >> 2) * 64, tbuf, t); }
        else                { int tt = blk - 80; tpose64(Wf2, 256, wf2T, 16, (tt >> 2) * 64, (tt & 3) * 64, tbuf, t); }
    } else if (blk < 240) {
        int i = blk - 112;
        float x = intent_q[(size_t)i * 256 + t];
        buf[t] = x;
        float ss = x * x;
#pragma unroll
        for (int m = 1; m < 64; m <<= 1) ss += __shfl_xor(ss, m, 64);
        if (lane == 0) red[w] = ss;
        __syncthreads();
        float tot = red[0] + red[1] + red[2] + red[3];
        qn[(size_t)i * 256 + t] = x / fmaxf(sqrtf(tot), 1e-12f);
        float acc = bqi[t] + bqs[t];
        for (int e = 0; e < 256; e += 4) {
            const float4 q4 = *(const float4*)&buf[e];
            acc += q4.x * Wqi[(size_t)(e + 0) * 256 + t];
            acc += q4.y * Wqi[(size_t)(e + 1) * 256 + t];
            acc += q4.z * Wqi[(size_t)(e + 2) * 256 + t];
            acc += q4.w * Wqi[(size_t)(e + 3) * 256 + t];
        }
        qint2[(size_t)i * 256 + t] = acc;
    } else {
        int b = blk - 240;
        float x = cls_embed[(size_t)b * 256 + t];
        float ss = x * x;
#pragma unroll
        for (int m = 1; m < 64; m <<= 1) ss += __shfl_xor(ss, m, 64);
        if (lane == 0) red[w] = ss;
        __syncthreads();
        float tot = red[0] + red[1] + red[2] + red[3];
        clsn[(size_t)b * 256 + t] = x / fmaxf(sqrtf(tot), 1e-12f);
    }
}

// ---------------------------------------------------------------------------
// kvf_k: fused tokens->f16 + K-proj + V-proj. grid 256 x 512 threads.
// ---------------------------------------------------------------------------
__global__ __launch_bounds__(512, 2) void kvf_k(
    const float* __restrict__ tokens,
    const _Float16* __restrict__ wkT, const _Float16* __restrict__ wvT,
    const float* __restrict__ bk, const float* __restrict__ bv,
    _Float16* __restrict__ kT, _Float16* __restrict__ vT)
{
    __shared__ __align__(16) _Float16 Sb[2][8192];   // 2 x 16KB: 32 rows x 256d tiled

    const int t = threadIdx.x, lane = t & 63, w = t >> 6;
    const int l15 = lane & 15, quad = lane >> 4;
    const int lofs = l15 * 32 + quad * 8;
    const int lofsA = ((l15 * 4 + quad) ^ ((l15 >> 1) & 7)) * 8;
    const int bx = blockIdx.x;
    const int b = bx & 31, chunk = bx >> 5;

    f16x8 wk[2][8], wv[2][8];
#pragma unroll
    for (int j = 0; j < 2; j++)
#pragma unroll
        for (int ks = 0; ks < 8; ks++) {
            wk[j][ks] = *(const f16x8*)(wkT + ((size_t)(2 * w + j) * 8 + ks) * 512 + lofs);
            wv[j][ks] = *(const f16x8*)(wvT + ((size_t)(2 * w + j) * 8 + ks) * 512 + lofs);
        }
    f32x4 bi0 = *(const f32x4*)(bk + w * 32 + quad * 4);
    f32x4 bi1 = *(const f32x4*)(bk + w * 32 + 16 + quad * 4);
    const float bv0 = bv[(2 * w) * 16 + l15];
    const float bv1 = bv[(2 * w + 1) * 16 + l15];

    const int rr = t >> 5, d8 = t & 31;
    const float* tbase = tokens + ((size_t)b * 2048 + chunk * 256) * 256 + rr * 256 + d8 * 8;
    const int mskW = ((rr >> 1) & 7) ^ (((d8 >> 2) & 3) << 1);
    const int wofs0 = (d8 >> 2) * 512 + (((rr * 4 + (d8 & 3)) ^ mskW) * 8);
    const int wofs1 = wofs0 + 8 * 512;

    float4 pa0, pa1, pb0, pb1;

#define KVF_LOADS(P) do {                                                    \
        const float* sp_ = tbase + (size_t)(P) * 8192;                       \
        pa0 = *(const float4*)(sp_);                                         \
        pa1 = *(const float4*)(sp_ + 4);                                     \
        pb0 = *(const float4*)(sp_ + 4096);                                  \
        pb1 = *(const float4*)(sp_ + 4100);                                  \
    } while (0)

#define KVF_STAGE(BUF) do {                                                  \
        f16x8 h0, h1;                                                        \
        h0[0] = (_Float16)pa0.x; h0[1] = (_Float16)pa0.y;                    \
        h0[2] = (_Float16)pa0.z; h0[3] = (_Float16)pa0.w;                    \
        h0[4] = (_Float16)pa1.x; h0[5] = (_Float16)pa1.y;                    \
        h0[6] = (_Float16)pa1.z; h0[7] = (_Float16)pa1.w;                    \
        h1[0] = (_Float16)pb0.x; h1[1] = (_Float16)pb0.y;                    \
        h1[2] = (_Float16)pb0.z; h1[3] = (_Float16)pb0.w;                    \
        h1[4] = (_Float16)pb1.x; h1[5] = (_Float16)pb1.y;                    \
        h1[6] = (_Float16)pb1.z; h1[7] = (_Float16)pb1.w;                    \
        *(f16x8*)((BUF) + wofs0) = h0;                                       \
        *(f16x8*)((BUF) + wofs1) = h1;                                       \
    } while (0)

    KVF_LOADS(0);
    KVF_STAGE(&Sb[0][0]);
    LGKM_BAR();

    for (int p = 0; p < 8; p++) {
        if (p < 7) KVF_LOADS(p + 1);
        __builtin_amdgcn_sched_barrier(0);

        const _Float16* lb = &Sb[p & 1][0];
        const int stg0 = chunk * 16 + p * 2;
        const int sp = chunk * 8 + p;

        f16x8 a[2][8];
#pragma unroll
        for (int st = 0; st < 2; st++)
#pragma unroll
            for (int ks = 0; ks < 8; ks++)
                a[st][ks] = *(const f16x8*)(lb + (st * 8 + ks) * 512 + (lofsA ^ ((ks & 3) * 16)));

        // K: c[row=dim][col=seq]
#pragma unroll
        for (int st = 0; st < 2; st++) {
            f32x4 c0 = {0.f, 0.f, 0.f, 0.f}, c1 = {0.f, 0.f, 0.f, 0.f};
#pragma unroll
            for (int ks = 0; ks < 8; ks++) {
                c0 = MFMA16(wk[0][ks], a[st][ks], c0);
                c1 = MFMA16(wk[1][ks], a[st][ks], c1);
            }
            f16x4 p0, p1;
#pragma unroll
            for (int reg = 0; reg < 4; reg++) {
                p0[reg] = (_Float16)(c0[reg] + bi0[reg]);
                p1[reg] = (_Float16)(c1[reg] + bi1[reg]);
            }
            _Float16* tp = kT + ((size_t)(b * 128 + stg0 + st) * 8 + w) * 512 + l15 * 32;
            *(f16x4*)(tp + (quad >> 1) * 8 + (quad & 1) * 4) = p0;
            *(f16x4*)(tp + (2 + (quad >> 1)) * 8 + (quad & 1) * 4) = p1;
        }

        // V: c[row=seq][col=dim]
#pragma unroll
        for (int j = 0; j < 2; j++) {
            f32x4 c0 = {0.f, 0.f, 0.f, 0.f}, c1 = {0.f, 0.f, 0.f, 0.f};
#pragma unroll
            for (int ks = 0; ks < 8; ks++) {
                c0 = MFMA16(a[0][ks], wv[j][ks], c0);
                c1 = MFMA16(a[1][ks], wv[j][ks], c1);
            }
            const float bb = j ? bv1 : bv0;
            f16x4 p0, p1;
#pragma unroll
            for (int reg = 0; reg < 4; reg++) {
                p0[reg] = (_Float16)(c0[reg] + bb);
                p1[reg] = (_Float16)(c1[reg] + bb);
            }
            _Float16* tp = vT + ((size_t)(b * 16 + 2 * w + j) * 64 + sp) * 512 + l15 * 32;
            *(f16x4*)(tp + (quad >> 1) * 8 + (quad & 1) * 4) = p0;
            *(f16x4*)(tp + (2 + (quad >> 1)) * 8 + (quad & 1) * 4) = p1;
        }

        if (p < 7) {
            KVF_STAGE(&Sb[(p + 1) & 1][0]);
            LGKM_BAR();
        }
    }
#undef KVF_LOADS
#undef KVF_STAGE
}

// ---------------------------------------------------------------------------
// slotq_k: fused slots-init + qslot. grid 1024 x 256: block = one row-tile.
// ---------------------------------------------------------------------------
__global__ __launch_bounds__(256, 4) void slotq_k(
    const float* __restrict__ noise, const float* __restrict__ slot_mu,
    const float* __restrict__ slot_sigma,
    const _Float16* __restrict__ wqsT, const float* __restrict__ qint2,
    float* __restrict__ slots, _Float16* __restrict__ qsT)
{
    __shared__ float sb[16 * 256];
    const int tid = threadIdx.x, lane = tid & 63, w4 = tid >> 6;
    const int l15 = lane & 15, quad = lane >> 4;
    const int lofs = l15 * 32 + quad * 8;
    const int rt = blockIdx.x;
    const int gr0 = rt * 16;

    {
        const int lr = w4 * 4 + quad;
        const int gr = gr0 + lr;
        const int b = gr >> 9, i = (gr >> 2) & 127, n = gr & 3;
        const float* np = noise + (((size_t)i * BSZ + b) * 4 + n) * 256;
#pragma unroll
        for (int k = 0; k < 4; k++) {
            const int c = k * 64 + l15 * 4;
            float4 mu = *(const float4*)(slot_mu + n * 256 + c);
            float4 sg = *(const float4*)(slot_sigma + n * 256 + c);
            float4 ns = *(const float4*)(np + c);
            float4 o;
            o.x = mu.x + ns.x * sg.x; o.y = mu.y + ns.y * sg.y;
            o.z = mu.z + ns.z * sg.z; o.w = mu.w + ns.w * sg.w;
            *slp(sb, lr, c) = o;
            *(float4*)(slots + (size_t)gr * 256 + c) = o;
        }
    }
    __syncthreads();

    f16x8 bs[8];
#pragma unroll
    for (int ks = 0; ks < 8; ks++) {
        const int c0 = ks * 32 + quad * 8;
        float4 xa = *slp(sb, l15, c0);
        float4 xb = *slp(sb, l15, c0 + 4);
        bs[ks][0] = (_Float16)xa.x; bs[ks][1] = (_Float16)xa.y;
        bs[ks][2] = (_Float16)xa.z; bs[ks][3] = (_Float16)xa.w;
        bs[ks][4] = (_Float16)xb.x; bs[ks][5] = (_Float16)xb.y;
        bs[ks][6] = (_Float16)xb.z; bs[ks][7] = (_Float16)xb.w;
    }
    const int iq = ((gr0 + l15) & 511) >> 2;
#pragma unroll
    for (int d = 0; d < 4; d++) {
        const int dti = w4 * 4 + d;
        f32x4 c = {0.f, 0.f, 0.f, 0.f};
#pragma unroll
        for (int ks = 0; ks < 8; ks++)
            c = MFMA16(*(const f16x8*)(wqsT + ((size_t)dti * 8 + ks) * 512 + lofs), bs[ks], c);
        float4 qi = *(const float4*)(qint2 + (size_t)iq * 256 + dti * 16 + quad * 4);
        f16x4 o;
#pragma unroll
        for (int reg = 0; reg < 4; reg++) o[reg] = (_Float16)((c[reg] + qi[reg]) * 0.0625f);
        *(f16x4*)(qsT + ((size_t)rt * 8 + (dti >> 1)) * 512 + l15 * 32
                  + ((dti & 1) * 2 + (quad >> 1)) * 8 + (quad & 1) * 4) = o;
    }
}

// ---------------------------------------------------------------------------
// attn_k: 4-wave blocks, 32 rows/wave (2 row-tiles) -> each K/V fragment
// feeds 2 MFMAs (LDS traffic per row halved vs r7), 2 blocks/CU.
// grid 512 x 256: b = bx&31, rb = (bx>>5)&3, sk = bx>>7. 32-key substeps x16.
// Accumulation chains identical to r5/r7 -> bitwise-same Opart/psum4.
// ---------------------------------------------------------------------------
__global__ __launch_bounds__(256, 2) void attn_k(
    const _Float16* __restrict__ qsT, const _Float16* __restrict__ kT,
    const _Float16* __restrict__ vT,
    _Float16* __restrict__ Opart, float* __restrict__ psum4)
{
    __shared__ __align__(16) _Float16 arena[24576];  // Kb[2][8192] | Vb[8192], 48KB
    __shared__ __align__(16) _Float16 pb[4][1280];   // per-wave P: 32 x 40, 10KB

    _Float16* KbA = arena;              // 2 x 8192 halves (32 keys x 256d each)
    _Float16* VbA = arena + 16384;      // 8192 halves (16 d-tiles x 32 keys)

    const int tid = threadIdx.x, lane = tid & 63, wv = tid >> 6;
    const int l15 = lane & 15, quad = lane >> 4;
    const int lofs = l15 * 32 + quad * 8;
    const int lofsA = ((l15 * 4 + quad) ^ ((l15 >> 1) & 7)) * 8;
    const int lnsw = (lane ^ ((lane >> 3) & 7)) * 8;
    const int bx = blockIdx.x;
    const int b = bx & 31, rb = (bx >> 5) & 3, sk = bx >> 7;
    const int gr0 = b * 512 + rb * 128 + wv * 32;
    const int rt_q = gr0 >> 4;

    _Float16* pw = pb[wv];

    const _Float16* kSrc = kT + ((size_t)(b * 128 + sk * 32) * 8) * 512;
    const _Float16* vSrc = vT + ((size_t)(b * 16) * 64 + sk * 16) * 512;

    // prologue: K(0) — 16 x 1KB tiles, 4 per wave
#pragma unroll
    for (int j = 0; j < 4; j++) {
        const int ee = wv * 4 + j;
        GLL(kSrc + (size_t)((ee >> 3) * 8 + (ee & 7)) * 512 + lnsw,
            KbA + ee * 512 + lane * 8);
    }

    f16x8 q[2][8];
#pragma unroll
    for (int m = 0; m < 2; m++)
#pragma unroll
        for (int ks = 0; ks < 8; ks++)
            q[m][ks] = *(const f16x8*)(qsT + ((size_t)(rt_q + m) * 8 + ks) * 512 + lofs);

    f32x4 O[2][16];
#pragma unroll
    for (int m = 0; m < 2; m++)
#pragma unroll
        for (int dt = 0; dt < 16; dt++) O[m][dt] = (f32x4){0.f, 0.f, 0.f, 0.f};
    float ps[2][4] = {{0.f, 0.f, 0.f, 0.f}, {0.f, 0.f, 0.f, 0.f}};

    asm volatile("s_waitcnt vmcnt(0)" ::: "memory");
    __builtin_amdgcn_s_barrier();
    __builtin_amdgcn_sched_barrier(0);

    for (int ss = 0; ss < 16; ss++) {
        const int cur = ss & 1;

        // stage V(ss): 16 d-tiles of 32 keys, 4 per wave
#pragma unroll
        for (int j = 0; j < 4; j++) {
            const int ee = wv * 4 + j;
            GLL(vSrc + (size_t)(ee * 64 + ss) * 512 + lnsw, VbA + ee * 512 + lane * 8);
        }
        if (ss < 15) {
#pragma unroll
            for (int j = 0; j < 4; j++) {
                const int ee = wv * 4 + j;
                GLL(kSrc + (size_t)((2 * (ss + 1) + (ee >> 3)) * 8 + (ee & 7)) * 512 + lnsw,
                    KbA + (cur ^ 1) * 8192 + ee * 512 + lane * 8);
            }
            // outstanding: [K(ss)<=4][V(ss)=4][K(ss+1)=4] -> wait K(ss)
            asm volatile("s_waitcnt vmcnt(8)" ::: "memory");
        } else {
            asm volatile("s_waitcnt vmcnt(4)" ::: "memory");
        }
        __builtin_amdgcn_s_barrier();
        __builtin_amdgcn_sched_barrier(0);

        // QK: 2 key-16-tiles; each K fragment feeds both row-tiles
#pragma unroll
        for (int kt = 0; kt < 2; kt++) {
            const _Float16* kp = KbA + cur * 8192 + (kt * 8) * 512;
            f32x4 c0 = {0.f, 0.f, 0.f, 0.f}, c1 = {0.f, 0.f, 0.f, 0.f};
#pragma unroll
            for (int ks = 0; ks < 8; ks++) {
                f16x8 kf = *(const f16x8*)(kp + ks * 512 + lofsA);
                c0 = MFMA16(q[0][ks], kf, c0);
                c1 = MFMA16(q[1][ks], kf, c1);
            }
            const int col = kt * 16 + l15;
#pragma unroll
            for (int reg = 0; reg < 4; reg++) {
                float p0 = __expf(fminf(c0[reg], 10.5f));
                float p1 = __expf(fminf(c1[reg], 10.5f));
                ps[0][reg] += p0;
                ps[1][reg] += p1;
                pw[(quad * 4 + reg) * 40 + col] = (_Float16)p0;
                pw[(16 + quad * 4 + reg) * 40 + col] = (_Float16)p1;
            }
        }

        __builtin_amdgcn_sched_barrier(0);
        asm volatile("s_waitcnt lgkmcnt(0)" ::: "memory");   // own-wave P visible
        if (ss < 15) {
            asm volatile("s_waitcnt vmcnt(4)" ::: "memory"); // V landed, K flying
        } else {
            asm volatile("s_waitcnt vmcnt(0)" ::: "memory");
        }
        __builtin_amdgcn_s_barrier();
        __builtin_amdgcn_sched_barrier(0);

        // PV: 16 dim-tiles; each V fragment feeds both row-tiles
        {
            f16x8 pa0 = *(const f16x8*)(pw + l15 * 40 + quad * 8);
            f16x8 pa1 = *(const f16x8*)(pw + (16 + l15) * 40 + quad * 8);
#pragma unroll
            for (int dt = 0; dt < 16; dt++) {
                f16x8 vf = *(const f16x8*)(VbA + dt * 512 + lofsA);
                O[0][dt] = MFMA16(pa0, vf, O[0][dt]);
                O[1][dt] = MFMA16(pa1, vf, O[1][dt]);
            }
        }
        __builtin_amdgcn_sched_barrier(0);
        __builtin_amdgcn_s_barrier();
        __builtin_amdgcn_sched_barrier(0);
    }

    // psum reduce over l15 (key) axis
#pragma unroll
    for (int m = 0; m < 2; m++) {
#pragma unroll
        for (int msk = 1; msk <= 8; msk <<= 1)
#pragma unroll
            for (int reg = 0; reg < 4; reg++) ps[m][reg] += __shfl_xor(ps[m][reg], msk, 64);
        if (l15 == 0) {
#pragma unroll
            for (int reg = 0; reg < 4; reg++)
                psum4[(size_t)sk * 16384 + gr0 + m * 16 + quad * 4 + reg] = ps[m][reg];
        }
    }

    // O transpose via per-wave scratch in the (now dead) K/V arena
    _Float16* ow = arena + wv * 2176;   // 16 x 136 halves per wave
#pragma unroll
    for (int m = 0; m < 2; m++) {
#pragma unroll
        for (int hd = 0; hd < 2; hd++) {
#pragma unroll
            for (int dt = 0; dt < 8; dt++) {
                const int dti = hd * 8 + dt;
#pragma unroll
                for (int reg = 0; reg < 4; reg++)
                    ow[(quad * 4 + reg) * 136 + dt * 16 + l15] = (_Float16)O[m][dti][reg];
            }
#pragma unroll
            for (int p2 = 0; p2 < 4; p2++) {
                const int u = lane + p2 * 64;
                const int row = u >> 4, col8 = u & 15;
                *(f16x8*)(Opart + ((size_t)sk * 16384 + gr0 + m * 16 + row) * 256 + hd * 128 + col8 * 8) =
                    *(const f16x8*)(ow + row * 136 + col8 * 8);
            }
        }
    }
}

// ---------------------------------------------------------------------------
// mlp_k: fused LN1+LN2+FFN1+FFN2 (+qslot | final). grid 512 x 256 threads.
// Block owns 32 rows (2 row-tiles): b = bx&31, rg = bx>>5 (0..15).
// Every weight fragment is loaded once and applied to BOTH row-tiles ->
// weight L2 traffic halved. LDS ~66KB -> 2 blocks/CU.
// Per-element arithmetic identical to prior mlp_k.
// ---------------------------------------------------------------------------
__global__ __launch_bounds__(256, 2) void mlp_k(
    const _Float16* __restrict__ Opart, const float* __restrict__ psum4,
    float* __restrict__ slots,
    const float* __restrict__ ln1_g, const float* __restrict__ ln1_b,
    const float* __restrict__ ln2_g, const float* __restrict__ ln2_b,
    const _Float16* __restrict__ wf1T, const float* __restrict__ bf1,
    const _Float16* __restrict__ wf2T, const float* __restrict__ bf2,
    const _Float16* __restrict__ wqsT, const float* __restrict__ qint2,
    _Float16* __restrict__ qsT,
    const float* __restrict__ qn, const float* __restrict__ clsn,
    const float* __restrict__ alphap, const float* __restrict__ tempp,
    float* __restrict__ out, int it)
{
    __shared__ float sl[32 * 256];                 // 32KB swizzled x1/slots
    __shared__ float2 st2[32];                     // LN2 stats per row
    __shared__ __align__(16) _Float16 actL[16384]; // 32KB act tiled (swizzled)

    const int tid = threadIdx.x, lane = tid & 63, w4 = tid >> 6;
    const int l15 = lane & 15, quad = lane >> 4;
    const int lofs = l15 * 32 + quad * 8;
    const int lofsA = ((l15 * 4 + quad) ^ ((l15 >> 1) & 7)) * 8;
    const int bx = blockIdx.x;
    const int b = bx & 31, rg = bx >> 5;
    const int R0 = b * 512 + rg * 32;

    // ---- phase 1: y = slots + O/psum; x1 = LN1(y) -> sl; LN2 stats -> st2
#pragma unroll
    for (int r2 = 0; r2 < 2; r2++) {
        const int lr = w4 * 8 + r2 * 4 + quad;
        const int gr = R0 + lr;
        float l = 0.f;
#pragma unroll
        for (int j = 0; j < 4; j++) l += psum4[(size_t)j * 16384 + gr];
        const float invl = 1.f / l;
        float4 y[4];
        float sm = 0.f, sq = 0.f;
#pragma unroll
        for (int k = 0; k < 4; k++) {
            const int c = k * 64 + l15 * 4;
            float4 o4 = {0.f, 0.f, 0.f, 0.f};
#pragma unroll
            for (int j = 0; j < 4; j++) {
                f16x4 p = *(const f16x4*)(Opart + ((size_t)j * 16384 + gr) * 256 + c);
                o4.x += (float)p[0]; o4.y += (float)p[1];
                o4.z += (float)p[2]; o4.w += (float)p[3];
            }
            float4 s4 = *(const float4*)(slots + (size_t)gr * 256 + c);
            y[k].x = s4.x + o4.x * invl; y[k].y = s4.y + o4.y * invl;
            y[k].z = s4.z + o4.z * invl; y[k].w = s4.w + o4.w * invl;
            sm += y[k].x + y[k].y + y[k].z + y[k].w;
            sq += dot4f(y[k], y[k]);
        }
#pragma unroll
        for (int m = 1; m <= 8; m <<= 1) { sm += __shfl_xor(sm, m, 64); sq += __shfl_xor(sq, m, 64); }
        const float mean = sm * (1.f / 256.f);
        const float rstd = rsqrtf(sq * (1.f / 256.f) - mean * mean + 1e-5f);
        float sm2 = 0.f, sq2 = 0.f;
#pragma unroll
        for (int k = 0; k < 4; k++) {
            const int c = k * 64 + l15 * 4;
            float4 g1 = *(const float4*)(ln1_g + c);
            float4 b1 = *(const float4*)(ln1_b + c);
            float4 x1;
            x1.x = (y[k].x - mean) * rstd * g1.x + b1.x;
            x1.y = (y[k].y - mean) * rstd * g1.y + b1.y;
            x1.z = (y[k].z - mean) * rstd * g1.z + b1.z;
            x1.w = (y[k].w - mean) * rstd * g1.w + b1.w;
            *slp(sl, lr, c) = x1;
            sm2 += x1.x + x1.y + x1.z + x1.w;
            sq2 += dot4f(x1, x1);
        }
#pragma unroll
        for (int m = 1; m <= 8; m <<= 1) { sm2 += __shfl_xor(sm2, m, 64); sq2 += __shfl_xor(sq2, m, 64); }
        const float mean2 = sm2 * (1.f / 256.f);
        const float rstd2 = rsqrtf(sq2 * (1.f / 256.f) - mean2 * mean2 + 1e-5f);
        if (l15 == 0) st2[lr] = make_float2(mean2, rstd2);
    }
    __syncthreads();

    // ---- phase 2: act = gelu(LN2(x1)@Wf1+bf1); wave w4 owns htis w4*8..+7,
    // each weight fragment applied to both row-tiles
    {
        f16x8 bh[2][8];
#pragma unroll
        for (int tt = 0; tt < 2; tt++) {
            const float2 s2 = st2[tt * 16 + l15];
#pragma unroll
            for (int ks = 0; ks < 8; ks++) {
                const int c0 = ks * 32 + quad * 8;
                float4 xa = *slp(sl, tt * 16 + l15, c0);
                float4 xb = *slp(sl, tt * 16 + l15, c0 + 4);
                float4 ga = *(const float4*)(ln2_g + c0);
                float4 gb = *(const float4*)(ln2_g + c0 + 4);
                float4 ba = *(const float4*)(ln2_b + c0);
                float4 bb2 = *(const float4*)(ln2_b + c0 + 4);
                bh[tt][ks][0] = (_Float16)((xa.x - s2.x) * s2.y * ga.x + ba.x);
                bh[tt][ks][1] = (_Float16)((xa.y - s2.x) * s2.y * ga.y + ba.y);
                bh[tt][ks][2] = (_Float16)((xa.z - s2.x) * s2.y * ga.z + ba.z);
                bh[tt][ks][3] = (_Float16)((xa.w - s2.x) * s2.y * ga.w + ba.w);
                bh[tt][ks][4] = (_Float16)((xb.x - s2.x) * s2.y * gb.x + bb2.x);
                bh[tt][ks][5] = (_Float16)((xb.y - s2.x) * s2.y * gb.y + bb2.y);
                bh[tt][ks][6] = (_Float16)((xb.z - s2.x) * s2.y * gb.z + bb2.z);
                bh[tt][ks][7] = (_Float16)((xb.w - s2.x) * s2.y * gb.w + bb2.w);
            }
        }
#pragma unroll 2
        for (int t8 = 0; t8 < 8; t8++) {
            const int hti = w4 * 8 + t8;
            f32x4 c0 = {0.f, 0.f, 0.f, 0.f}, c1 = {0.f, 0.f, 0.f, 0.f};
#pragma unroll
            for (int ks = 0; ks < 8; ks++) {
                f16x8 wfrag = *(const f16x8*)(wf1T + ((size_t)hti * 8 + ks) * 512 + lofs);
                c0 = MFMA16(wfrag, bh[0][ks], c0);
                c1 = MFMA16(wfrag, bh[1][ks], c1);
            }
            float4 bb = *(const float4*)(bf1 + hti * 16 + quad * 4);
            f16x4 o0, o1;
#pragma unroll
            for (int reg = 0; reg < 4; reg++) {
                float xg0 = c0[reg] + bb[reg];
                float xg1 = c1[reg] + bb[reg];
                o0[reg] = (_Float16)(0.5f * xg0 * (1.f + erff(xg0 * 0.70710678118654752f)));
                o1[reg] = (_Float16)(0.5f * xg1 * (1.f + erff(xg1 * 0.70710678118654752f)));
            }
            const int gA = l15 * 4 + (hti & 1) * 2 + (quad >> 1);
            const int aofs = ((size_t)(hti >> 1)) * 512 + ((gA ^ ((l15 >> 1) & 7)) * 8) + (quad & 1) * 4;
            *(f16x4*)(actL + aofs) = o0;
            *(f16x4*)(actL + 8192 + aofs) = o1;
        }
    }
    __syncthreads();

    // ---- phase 3: slots_new = x1 + act@Wf2 + bf2 -> sl; weight shared
    {
        f32x4 c[2][4];
#pragma unroll
        for (int tt = 0; tt < 2; tt++)
#pragma unroll
            for (int d = 0; d < 4; d++) {
                const int dti = w4 * 4 + d;
                float4 x4 = *slp(sl, tt * 16 + l15, dti * 16 + quad * 4);
                float4 bb = *(const float4*)(bf2 + dti * 16 + quad * 4);
                c[tt][d] = (f32x4){x4.x + bb.x, x4.y + bb.y, x4.z + bb.z, x4.w + bb.w};
            }
        for (int ks = 0; ks < 16; ks++) {
            f16x8 a0 = *(const f16x8*)(actL + (size_t)ks * 512 + lofsA);
            f16x8 a1 = *(const f16x8*)(actL + 8192 + (size_t)ks * 512 + lofsA);
#pragma unroll
            for (int d = 0; d < 4; d++) {
                f16x8 wfrag = *(const f16x8*)(wf2T + ((size_t)(w4 * 4 + d) * 16 + ks) * 512 + lofs);
                c[0][d] = MFMA16(wfrag, a0, c[0][d]);
                c[1][d] = MFMA16(wfrag, a1, c[1][d]);
            }
        }
        __syncthreads();
#pragma unroll
        for (int tt = 0; tt < 2; tt++)
#pragma unroll
            for (int d = 0; d < 4; d++) {
                const int dti = w4 * 4 + d;
                float4 v = {c[tt][d][0], c[tt][d][1], c[tt][d][2], c[tt][d][3]};
                *slp(sl, tt * 16 + l15, dti * 16 + quad * 4) = v;
            }
    }
    __syncthreads();

    if (it < 2) {
        // ---- phase 4a: qsT for next iteration (weight shared across tiles)
        f16x8 bs[2][8];
#pragma unroll
        for (int tt = 0; tt < 2; tt++)
#pragma unroll
            for (int ks = 0; ks < 8; ks++) {
                const int c0 = ks * 32 + quad * 8;
                float4 xa = *slp(sl, tt * 16 + l15, c0);
                float4 xb = *slp(sl, tt * 16 + l15, c0 + 4);
                bs[tt][ks][0] = (_Float16)xa.x; bs[tt][ks][1] = (_Float16)xa.y;
                bs[tt][ks][2] = (_Float16)xa.z; bs[tt][ks][3] = (_Float16)xa.w;
                bs[tt][ks][4] = (_Float16)xb.x; bs[tt][ks][5] = (_Float16)xb.y;
                bs[tt][ks][6] = (_Float16)xb.z; bs[tt][ks][7] = (_Float16)xb.w;
            }
        const int iq0 = rg * 8 + (l15 >> 2);
        const int rtg0 = b * 32 + rg * 2;
#pragma unroll
        for (int d = 0; d < 4; d++) {
            const int dti = w4 * 4 + d;
            f32x4 c0 = {0.f, 0.f, 0.f, 0.f}, c1 = {0.f, 0.f, 0.f, 0.f};
#pragma unroll
            for (int ks = 0; ks < 8; ks++) {
                f16x8 wfrag = *(const f16x8*)(wqsT + ((size_t)dti * 8 + ks) * 512 + lofs);
                c0 = MFMA16(wfrag, bs[0][ks], c0);
                c1 = MFMA16(wfrag, bs[1][ks], c1);
            }
            float4 qi0 = *(const float4*)(qint2 + (size_t)iq0 * 256 + dti * 16 + quad * 4);
            float4 qi1 = *(const float4*)(qint2 + (size_t)(iq0 + 4) * 256 + dti * 16 + quad * 4);
            f16x4 o0, o1;
#pragma unroll
            for (int reg = 0; reg < 4; reg++) {
                o0[reg] = (_Float16)((c0[reg] + qi0[reg]) * 0.0625f);
                o1[reg] = (_Float16)((c1[reg] + qi1[reg]) * 0.0625f);
            }
            const int qofs = (dti >> 1) * 512 + l15 * 32
                           + ((dti & 1) * 2 + (quad >> 1)) * 8 + (quad & 1) * 4;
            *(f16x4*)(qsT + (size_t)rtg0 * 4096 + qofs) = o0;
            *(f16x4*)(qsT + (size_t)(rtg0 + 1) * 4096 + qofs) = o1;
        }
        // ---- phase 4b: slots_new -> global (coalesced)
        {
            const int lr2 = tid >> 3, k8 = tid & 7;
#pragma unroll
            for (int q4 = 0; q4 < 8; q4++) {
                float4 v = *slp(sl, lr2, k8 * 32 + q4 * 4);
                *(float4*)(slots + (size_t)(R0 + lr2) * 256 + k8 * 32 + q4 * 4) = v;
            }
        }
    } else {
        // ---- phase 4c: final scoring (2 intents per wave, 8 per block)
#pragma unroll
        for (int ii = 0; ii < 2; ii++) {
            const int i_loc = w4 * 2 + ii;
            const int i = rg * 8 + i_loc;
            float4 qv = *(const float4*)(qn + (size_t)i * 256 + lane * 4);
            float4 xs[4];
            float st4[4];
#pragma unroll
            for (int n = 0; n < 4; n++) {
                xs[n] = *slp(sl, i_loc * 4 + n, lane * 4);
                float ss = dot4f(xs[n], xs[n]);
                float sq = dot4f(xs[n], qv);
#pragma unroll
                for (int m = 1; m < 64; m <<= 1) { ss += __shfl_xor(ss, m, 64); sq += __shfl_xor(sq, m, 64); }
                st4[n] = sq / fmaxf(sqrtf(ss), 1e-12f);
            }
            float mx = fmaxf(fmaxf(st4[0], st4[1]), fmaxf(st4[2], st4[3]));
            float e0 = __expf(st4[0] - mx), e1 = __expf(st4[1] - mx);
            float e2 = __expf(st4[2] - mx), e3 = __expf(st4[3] - mx);
            float inv = 1.f / (e0 + e1 + e2 + e3);
            float4 smv;
            smv.x = (e0 * xs[0].x + e1 * xs[1].x + e2 * xs[2].x + e3 * xs[3].x) * inv;
            smv.y = (e0 * xs[0].y + e1 * xs[1].y + e2 * xs[2].y + e3 * xs[3].y) * inv;
            smv.z = (e0 * xs[0].z + e1 * xs[1].z + e2 * xs[2].z + e3 * xs[3].z) * inv;
            smv.w = (e0 * xs[0].w + e1 * xs[1].w + e2 * xs[2].w + e3 * xs[3].w) * inv;
            float ssm = dot4f(smv, smv);
            float sqn = dot4f(smv, qv);
            float4 cv = *(const float4*)(clsn + (size_t)b * 256 + lane * 4);
            float cq = dot4f(cv, qv);
#pragma unroll
            for (int m = 1; m < 64; m <<= 1) {
                ssm += __shfl_xor(ssm, m, 64);
                sqn += __shfl_xor(sqn, m, 64);
                cq  += __shfl_xor(cq,  m, 64);
            }
            if (lane == 0) {
                float score = cq + alphap[0] * sqn / fmaxf(sqrtf(ssm), 1e-12f);
                out[(size_t)b * NI + i] = score / fmaxf(tempp[0], 1e-4f);
            }
        }
    }
}

// ---------------------------------------------------------------------------
extern "C" void kernel_launch(void* const* d_in, const int* in_sizes, int n_in,
                              void* d_out, int out_size, void* d_ws, size_t ws_size,
                              hipStream_t stream)
{
    const float* tokens     = (const float*)d_in[0];
    const float* cls_embed  = (const float*)d_in[1];
    const float* intent_q   = (const float*)d_in[2];
    const float* noise      = (const float*)d_in[3];
    const float* Wk  = (const float*)d_in[4];
    const float* bk  = (const float*)d_in[5];
    const float* Wv  = (const float*)d_in[6];
    const float* bv  = (const float*)d_in[7];
    const float* Wqs = (const float*)d_in[8];
    const float* bqs = (const float*)d_in[9];
    const float* Wqi = (const float*)d_in[10];
    const float* bqi = (const float*)d_in[11];
    const float* ln1g = (const float*)d_in[12];
    const float* ln1b = (const float*)d_in[13];
    const float* ln2g = (const float*)d_in[14];
    const float* ln2b = (const float*)d_in[15];
    const float* Wf1 = (const float*)d_in[16];
    const float* bf1 = (const float*)d_in[17];
    const float* Wf2 = (const float*)d_in[18];
    const float* bf2 = (const float*)d_in[19];
    const float* slot_mu    = (const float*)d_in[20];
    const float* slot_sigma = (const float*)d_in[21];
    const float* alphap = (const float*)d_in[22];
    const float* tempp  = (const float*)d_in[23];
    float* out = (float*)d_out;

    char* base = (char*)d_ws;
    _Float16* qsT   = (_Float16*)(base);                        //  8388608 B
    _Float16* kT    = (_Float16*)(base + 33554432u);            // 33554432 B
    _Float16* vT    = (_Float16*)(base + 67108864u);            // 33554432 B
    _Float16* Opart = (_Float16*)(base + 100663296u);           // 33554432 B
    float* slots    = (float*)(base + 134217728u);              // 16777216 B
    _Float16* wkT   = (_Float16*)(base + 150994944u);           //   131072 B
    _Float16* wvT   = (_Float16*)(base + 151126016u);
    _Float16* wqsT  = (_Float16*)(base + 151257088u);
    _Float16* wf1T  = (_Float16*)(base + 151388160u);           //   262144 B
    _Float16* wf2T  = (_Float16*)(base + 151650304u);           //   262144 B
    float* qint2    = (float*)(base + 151912448u);              //   131072 B
    float* qnb      = (float*)(base + 152043520u);              //   131072 B
    float* clsn     = (float*)(base + 152174592u);              //    32768 B
    float* psum4    = (float*)(base + 152207360u);              //   262144 B

    prep<<<272, 256, 0, stream>>>(Wk, Wv, Wqs, Wf1, Wf2, intent_q, Wqi, bqi, bqs,
                                  cls_embed, wkT, wvT, wqsT, wf1T, wf2T,
                                  qint2, qnb, clsn);
    kvf_k<<<256, 512, 0, stream>>>(tokens, wkT, wvT, bk, bv, kT, vT);
    slotq_k<<<1024, 256, 0, stream>>>(noise, slot_mu, slot_sigma, wqsT, qint2,
                                      slots, qsT);

    for (int it = 0; it < 3; it++) {
        attn_k<<<512, 256, 0, stream>>>(qsT, kT, vT, Opart, psum4);
        mlp_k<<<512, 256, 0, stream>>>(Opart, psum4, slots,
                                       ln1g, ln1b, ln2g, ln2b,
                                       wf1T, bf1, wf2T, bf2,
                                       wqsT, qint2, qsT,
                                       qnb, clsn, alphap, tempp, out, it);
    }
}

// Round 9
// 435.579 us; speedup vs baseline: 1.9369x; 1.0057x over previous
//
#include <hip/hip_runtime.h>
#include <math.h>

#define BSZ 32
#define NI  128

typedef __attribute__((ext_vector_type(8))) _Float16 f16x8;
typedef __attribute__((ext_vector_type(4))) _Float16 f16x4;
typedef __attribute__((ext_vector_type(4))) float    f32x4;

// MFMA16(X, Y, C): C[row = quad*4+reg <- X's l15][col = l15 <- Y's l15]
// X,Y k-index = quad*8 + j.
// Tiled operand format: 1KB tiles, inner l15*32 + quad*8 + j for a fragment.
#define MFMA16(a, b, c) __builtin_amdgcn_mfma_f32_16x16x32_f16((a), (b), (c), 0, 0, 0)

// global -> LDS async DMA, 16B per lane, wave-linear dest
#define GLL(g, l) __builtin_amdgcn_global_load_lds(                          \
    (const __attribute__((address_space(1))) void*)(g),                      \
    (__attribute__((address_space(3))) void*)(l), 16, 0, 0)

// barrier that waits LDS ops only (leaves global loads/stores in flight)
#define LGKM_BAR() do {                                                      \
    asm volatile("s_waitcnt lgkmcnt(0)" ::: "memory");                       \
    __builtin_amdgcn_sched_barrier(0);                                       \
    __builtin_amdgcn_s_barrier();                                            \
    __builtin_amdgcn_sched_barrier(0); } while (0)

__device__ inline float dot4f(float4 a, float4 b) {
    return a.x * b.x + a.y * b.y + a.z * b.z + a.w * b.w;
}

// swizzled pointer into row-major f32 LDS: row r, col c (multiple of 4).
__device__ inline float4* slp(float* base, int r, int c) {
    return (float4*)(base + r * 256 + ((((c) >> 2) ^ (r & 7)) << 2));
}

// ---------------------------------------------------------------------------
// 64x64 f32->f16 transpose tile -> TILED output (element (n,k) from src[k][n])
// ---------------------------------------------------------------------------
__device__ inline void tpose64(const float* __restrict__ src, int Csrc,
                               _Float16* __restrict__ dstT, int KT,
                               int r0, int c0, _Float16 (*tbuf)[72], int tid)
{
#pragma unroll
    for (int it = 0; it < 4; it++) {
        int idx = tid + it * 256;
        int rr = idx >> 4, c4 = idx & 15;
        float4 w = *(const float4*)(src + (size_t)(r0 + rr) * Csrc + c0 + c4 * 4);
        tbuf[c4 * 4 + 0][rr] = (_Float16)w.x;
        tbuf[c4 * 4 + 1][rr] = (_Float16)w.y;
        tbuf[c4 * 4 + 2][rr] = (_Float16)w.z;
        tbuf[c4 * 4 + 3][rr] = (_Float16)w.w;
    }
    __syncthreads();
#pragma unroll
    for (int it = 0; it < 2; it++) {
        int idx = tid + it * 256;
        int orr = idx >> 3, oc8 = idx & 7;
        int n = c0 + orr;
        size_t tile = (size_t)(n >> 4) * KT + (r0 >> 5) + (oc8 >> 2);
        *(f16x8*)(dstT + tile * 512 + (n & 15) * 32 + (oc8 & 3) * 8) = *(const f16x8*)&tbuf[orr][oc8 * 8];
    }
}

// ---------------------------------------------------------------------------
// prep: tiled f16 weights, qn, cls_n, qint2 = q@Wqi + bqi + bqs
// ---------------------------------------------------------------------------
__global__ __launch_bounds__(256) void prep(
    const float* __restrict__ Wk, const float* __restrict__ Wv,
    const float* __restrict__ Wqs, const float* __restrict__ Wf1,
    const float* __restrict__ Wf2,
    const float* __restrict__ intent_q, const float* __restrict__ Wqi,
    const float* __restrict__ bqi, const float* __restrict__ bqs,
    const float* __restrict__ cls_embed,
    _Float16* __restrict__ wkT, _Float16* __restrict__ wvT,
    _Float16* __restrict__ wqsT, _Float16* __restrict__ wf1T,
    _Float16* __restrict__ wf2T,
    float* __restrict__ qint2, float* __restrict__ qn, float* __restrict__ clsn)
{
    __shared__ _Float16 tbuf[64][72];
    __shared__ float buf[256];
    __shared__ float red[4];
    const int t = threadIdx.x, blk = blockIdx.x;
    const int lane = t & 63, w = t >> 6;

    if (blk < 112) {
        if (blk < 16)       tpose64(Wk, 256, wkT, 8, (blk >> 2) * 64, (blk & 3) * 64, tbuf, t);
        else if (blk < 32)  { int tt = blk - 16; tpose64(Wv, 256, wvT, 8, (tt >> 2) * 64, (tt & 3) * 64, tbuf, t); }
        else if (blk < 48)  { int tt = blk - 32; tpose64(Wqs, 256, wqsT, 8, (tt >> 2) * 64, (tt & 3) * 64, tbuf, t); }
        else if (blk < 80)  { int tt = blk - 48; tpose64(Wf1, 512, wf1T, 8, (tt & 3) * 64, (tt >> 2) * 64, tbuf, t); }
        else                { int tt = blk - 80; tpose64(Wf2, 256, wf2T, 16, (tt >> 2) * 64, (tt & 3) * 64, tbuf, t); }
    } else if (blk < 240) {
        int i = blk - 112;
        float x = intent_q[(size_t)i * 256 + t];
        buf[t] = x;
        float ss = x * x;
#pragma unroll
        for (int m = 1; m < 64; m <<= 1) ss += __shfl_xor(ss, m, 64);
        if (lane == 0) red[w] = ss;
        __syncthreads();
        float tot = red[0] + red[1] + red[2] + red[3];
        qn[(size_t)i * 256 + t] = x / fmaxf(sqrtf(tot), 1e-12f);
        float acc = bqi[t] + bqs[t];
        for (int e = 0; e < 256; e += 4) {
            const float4 q4 = *(const float4*)&buf[e];
            acc += q4.x * Wqi[(size_t)(e + 0) * 256 + t];
            acc += q4.y * Wqi[(size_t)(e + 1) * 256 + t];
            acc += q4.z * Wqi[(size_t)(e + 2) * 256 + t];
            acc += q4.w * Wqi[(size_t)(e + 3) * 256 + t];
        }
        qint2[(size_t)i * 256 + t] = acc;
    } else {
        int b = blk - 240;
        float x = cls_embed[(size_t)b * 256 + t];
        float ss = x * x;
#pragma unroll
        for (int m = 1; m < 64; m <<= 1) ss += __shfl_xor(ss, m, 64);
        if (lane == 0) red[w] = ss;
        __syncthreads();
        float tot = red[0] + red[1] + red[2] + red[3];
        clsn[(size_t)b * 256 + t] = x / fmaxf(sqrtf(tot), 1e-12f);
    }
}

// ---------------------------------------------------------------------------
// kvf_k: fused tokens->f16 + K-proj + V-proj. grid 256 x 512 threads.
// ---------------------------------------------------------------------------
__global__ __launch_bounds__(512, 2) void kvf_k(
    const float* __restrict__ tokens,
    const _Float16* __restrict__ wkT, const _Float16* __restrict__ wvT,
    const float* __restrict__ bk, const float* __restrict__ bv,
    _Float16* __restrict__ kT, _Float16* __restrict__ vT)
{
    __shared__ __align__(16) _Float16 Sb[2][8192];   // 2 x 16KB: 32 rows x 256d tiled

    const int t = threadIdx.x, lane = t & 63, w = t >> 6;
    const int l15 = lane & 15, quad = lane >> 4;
    const int lofs = l15 * 32 + quad * 8;
    const int lofsA = ((l15 * 4 + quad) ^ ((l15 >> 1) & 7)) * 8;
    const int bx = blockIdx.x;
    const int b = bx & 31, chunk = bx >> 5;

    f16x8 wk[2][8], wv[2][8];
#pragma unroll
    for (int j = 0; j < 2; j++)
#pragma unroll
        for (int ks = 0; ks < 8; ks++) {
            wk[j][ks] = *(const f16x8*)(wkT + ((size_t)(2 * w + j) * 8 + ks) * 512 + lofs);
            wv[j][ks] = *(const f16x8*)(wvT + ((size_t)(2 * w + j) * 8 + ks) * 512 + lofs);
        }
    f32x4 bi0 = *(const f32x4*)(bk + w * 32 + quad * 4);
    f32x4 bi1 = *(const f32x4*)(bk + w * 32 + 16 + quad * 4);
    const float bv0 = bv[(2 * w) * 16 + l15];
    const float bv1 = bv[(2 * w + 1) * 16 + l15];

    const int rr = t >> 5, d8 = t & 31;
    const float* tbase = tokens + ((size_t)b * 2048 + chunk * 256) * 256 + rr * 256 + d8 * 8;
    const int mskW = ((rr >> 1) & 7) ^ (((d8 >> 2) & 3) << 1);
    const int wofs0 = (d8 >> 2) * 512 + (((rr * 4 + (d8 & 3)) ^ mskW) * 8);
    const int wofs1 = wofs0 + 8 * 512;

    float4 pa0, pa1, pb0, pb1;

#define KVF_LOADS(P) do {                                                    \
        const float* sp_ = tbase + (size_t)(P) * 8192;                       \
        pa0 = *(const float4*)(sp_);                                         \
        pa1 = *(const float4*)(sp_ + 4);                                     \
        pb0 = *(const float4*)(sp_ + 4096);                                  \
        pb1 = *(const float4*)(sp_ + 4100);                                  \
    } while (0)

#define KVF_STAGE(BUF) do {                                                  \
        f16x8 h0, h1;                                                        \
        h0[0] = (_Float16)pa0.x; h0[1] = (_Float16)pa0.y;                    \
        h0[2] = (_Float16)pa0.z; h0[3] = (_Float16)pa0.w;                    \
        h0[4] = (_Float16)pa1.x; h0[5] = (_Float16)pa1.y;                    \
        h0[6] = (_Float16)pa1.z; h0[7] = (_Float16)pa1.w;                    \
        h1[0] = (_Float16)pb0.x; h1[1] = (_Float16)pb0.y;                    \
        h1[2] = (_Float16)pb0.z; h1[3] = (_Float16)pb0.w;                    \
        h1[4] = (_Float16)pb1.x; h1[5] = (_Float16)pb1.y;                    \
        h1[6] = (_Float16)pb1.z; h1[7] = (_Float16)pb1.w;                    \
        *(f16x8*)((BUF) + wofs0) = h0;                                       \
        *(f16x8*)((BUF) + wofs1) = h1;                                       \
    } while (0)

    KVF_LOADS(0);
    KVF_STAGE(&Sb[0][0]);
    LGKM_BAR();

    for (int p = 0; p < 8; p++) {
        if (p < 7) KVF_LOADS(p + 1);
        __builtin_amdgcn_sched_barrier(0);

        const _Float16* lb = &Sb[p & 1][0];
        const int stg0 = chunk * 16 + p * 2;
        const int sp = chunk * 8 + p;

        f16x8 a[2][8];
#pragma unroll
        for (int st = 0; st < 2; st++)
#pragma unroll
            for (int ks = 0; ks < 8; ks++)
                a[st][ks] = *(const f16x8*)(lb + (st * 8 + ks) * 512 + (lofsA ^ ((ks & 3) * 16)));

        // K: c[row=dim][col=seq]
#pragma unroll
        for (int st = 0; st < 2; st++) {
            f32x4 c0 = {0.f, 0.f, 0.f, 0.f}, c1 = {0.f, 0.f, 0.f, 0.f};
#pragma unroll
            for (int ks = 0; ks < 8; ks++) {
                c0 = MFMA16(wk[0][ks], a[st][ks], c0);
                c1 = MFMA16(wk[1][ks], a[st][ks], c1);
            }
            f16x4 p0, p1;
#pragma unroll
            for (int reg = 0; reg < 4; reg++) {
                p0[reg] = (_Float16)(c0[reg] + bi0[reg]);
                p1[reg] = (_Float16)(c1[reg] + bi1[reg]);
            }
            _Float16* tp = kT + ((size_t)(b * 128 + stg0 + st) * 8 + w) * 512 + l15 * 32;
            *(f16x4*)(tp + (quad >> 1) * 8 + (quad & 1) * 4) = p0;
            *(f16x4*)(tp + (2 + (quad >> 1)) * 8 + (quad & 1) * 4) = p1;
        }

        // V: c[row=seq][col=dim]
#pragma unroll
        for (int j = 0; j < 2; j++) {
            f32x4 c0 = {0.f, 0.f, 0.f, 0.f}, c1 = {0.f, 0.f, 0.f, 0.f};
#pragma unroll
            for (int ks = 0; ks < 8; ks++) {
                c0 = MFMA16(a[0][ks], wv[j][ks], c0);
                c1 = MFMA16(a[1][ks], wv[j][ks], c1);
            }
            const float bb = j ? bv1 : bv0;
            f16x4 p0, p1;
#pragma unroll
            for (int reg = 0; reg < 4; reg++) {
                p0[reg] = (_Float16)(c0[reg] + bb);
                p1[reg] = (_Float16)(c1[reg] + bb);
            }
            _Float16* tp = vT + ((size_t)(b * 16 + 2 * w + j) * 64 + sp) * 512 + l15 * 32;
            *(f16x4*)(tp + (quad >> 1) * 8 + (quad & 1) * 4) = p0;
            *(f16x4*)(tp + (2 + (quad >> 1)) * 8 + (quad & 1) * 4) = p1;
        }

        if (p < 7) {
            KVF_STAGE(&Sb[(p + 1) & 1][0]);
            LGKM_BAR();
        }
    }
#undef KVF_LOADS
#undef KVF_STAGE
}

// ---------------------------------------------------------------------------
// slotq_k: fused slots-init + qslot. grid 1024 x 256: block = one row-tile.
// ---------------------------------------------------------------------------
__global__ __launch_bounds__(256, 4) void slotq_k(
    const float* __restrict__ noise, const float* __restrict__ slot_mu,
    const float* __restrict__ slot_sigma,
    const _Float16* __restrict__ wqsT, const float* __restrict__ qint2,
    float* __restrict__ slots, _Float16* __restrict__ qsT)
{
    __shared__ float sb[16 * 256];
    const int tid = threadIdx.x, lane = tid & 63, w4 = tid >> 6;
    const int l15 = lane & 15, quad = lane >> 4;
    const int lofs = l15 * 32 + quad * 8;
    const int rt = blockIdx.x;
    const int gr0 = rt * 16;

    {
        const int lr = w4 * 4 + quad;
        const int gr = gr0 + lr;
        const int b = gr >> 9, i = (gr >> 2) & 127, n = gr & 3;
        const float* np = noise + (((size_t)i * BSZ + b) * 4 + n) * 256;
#pragma unroll
        for (int k = 0; k < 4; k++) {
            const int c = k * 64 + l15 * 4;
            float4 mu = *(const float4*)(slot_mu + n * 256 + c);
            float4 sg = *(const float4*)(slot_sigma + n * 256 + c);
            float4 ns = *(const float4*)(np + c);
            float4 o;
            o.x = mu.x + ns.x * sg.x; o.y = mu.y + ns.y * sg.y;
            o.z = mu.z + ns.z * sg.z; o.w = mu.w + ns.w * sg.w;
            *slp(sb, lr, c) = o;
            *(float4*)(slots + (size_t)gr * 256 + c) = o;
        }
    }
    __syncthreads();

    f16x8 bs[8];
#pragma unroll
    for (int ks = 0; ks < 8; ks++) {
        const int c0 = ks * 32 + quad * 8;
        float4 xa = *slp(sb, l15, c0);
        float4 xb = *slp(sb, l15, c0 + 4);
        bs[ks][0] = (_Float16)xa.x; bs[ks][1] = (_Float16)xa.y;
        bs[ks][2] = (_Float16)xa.z; bs[ks][3] = (_Float16)xa.w;
        bs[ks][4] = (_Float16)xb.x; bs[ks][5] = (_Float16)xb.y;
        bs[ks][6] = (_Float16)xb.z; bs[ks][7] = (_Float16)xb.w;
    }
    const int iq = ((gr0 + l15) & 511) >> 2;
#pragma unroll
    for (int d = 0; d < 4; d++) {
        const int dti = w4 * 4 + d;
        f32x4 c = {0.f, 0.f, 0.f, 0.f};
#pragma unroll
        for (int ks = 0; ks < 8; ks++)
            c = MFMA16(*(const f16x8*)(wqsT + ((size_t)dti * 8 + ks) * 512 + lofs), bs[ks], c);
        float4 qi = *(const float4*)(qint2 + (size_t)iq * 256 + dti * 16 + quad * 4);
        f16x4 o;
#pragma unroll
        for (int reg = 0; reg < 4; reg++) o[reg] = (_Float16)((c[reg] + qi[reg]) * 0.0625f);
        *(f16x4*)(qsT + ((size_t)rt * 8 + (dti >> 1)) * 512 + l15 * 32
                  + ((dti & 1) * 2 + (quad >> 1)) * 8 + (quad & 1) * 4) = o;
    }
}

// ---------------------------------------------------------------------------
// attn_k: single-barrier substeps. 4 waves x 32 rows, 2 blocks/CU.
// grid 512 x 256: b = bx&31, rb = (bx>>5)&3, sk = bx>>7. 32-key substeps x16.
// K AND V double-buffered, staged one substep ahead; P is per-wave (no
// cross-wave dep) so the mid-substep barrier is gone: 18 barriers vs 48.
// Accumulation chains identical to r8 -> bitwise-same Opart/psum4.
// ---------------------------------------------------------------------------
__global__ __launch_bounds__(256, 2) void attn_k(
    const _Float16* __restrict__ qsT, const _Float16* __restrict__ kT,
    const _Float16* __restrict__ vT,
    _Float16* __restrict__ Opart, float* __restrict__ psum4)
{
    __shared__ __align__(16) _Float16 KbS[2][8192];  // 32KB: 32 keys x 256d, dbuf
    __shared__ __align__(16) _Float16 VbS[2][8192];  // 32KB: 16 d-tiles x 32 keys, dbuf
    __shared__ __align__(16) _Float16 pb[4][1280];   // per-wave P: 32 x 40, 10KB

    const int tid = threadIdx.x, lane = tid & 63, wv = tid >> 6;
    const int l15 = lane & 15, quad = lane >> 4;
    const int lofs = l15 * 32 + quad * 8;
    const int lofsA = ((l15 * 4 + quad) ^ ((l15 >> 1) & 7)) * 8;
    const int lnsw = (lane ^ ((lane >> 3) & 7)) * 8;
    const int bx = blockIdx.x;
    const int b = bx & 31, rb = (bx >> 5) & 3, sk = bx >> 7;
    const int gr0 = b * 512 + rb * 128 + wv * 32;
    const int rt_q = gr0 >> 4;

    _Float16* pw = pb[wv];

    const _Float16* kSrc = kT + ((size_t)(b * 128 + sk * 32) * 8) * 512;
    const _Float16* vSrc = vT + ((size_t)(b * 16) * 64 + sk * 16) * 512;

    // prologue: K(0) + V(0)
#pragma unroll
    for (int j = 0; j < 4; j++) {
        const int ee = wv * 4 + j;
        GLL(kSrc + (size_t)((ee >> 3) * 8 + (ee & 7)) * 512 + lnsw,
            KbS[0] + ee * 512 + lane * 8);
    }
#pragma unroll
    for (int j = 0; j < 4; j++) {
        const int ee = wv * 4 + j;
        GLL(vSrc + (size_t)(ee * 64 + 0) * 512 + lnsw, VbS[0] + ee * 512 + lane * 8);
    }

    f16x8 q[2][8];
#pragma unroll
    for (int m = 0; m < 2; m++)
#pragma unroll
        for (int ks = 0; ks < 8; ks++)
            q[m][ks] = *(const f16x8*)(qsT + ((size_t)(rt_q + m) * 8 + ks) * 512 + lofs);

    f32x4 O[2][16];
#pragma unroll
    for (int m = 0; m < 2; m++)
#pragma unroll
        for (int dt = 0; dt < 16; dt++) O[m][dt] = (f32x4){0.f, 0.f, 0.f, 0.f};
    float ps[2][4] = {{0.f, 0.f, 0.f, 0.f}, {0.f, 0.f, 0.f, 0.f}};

    asm volatile("s_waitcnt vmcnt(0)" ::: "memory");
    __builtin_amdgcn_s_barrier();
    __builtin_amdgcn_sched_barrier(0);

    for (int ss = 0; ss < 16; ss++) {
        const int cur = ss & 1;

        // prefetch K(ss+1) + V(ss+1) into the other buffers (issued early;
        // latency hides under the 48 MFMAs below)
        if (ss < 15) {
#pragma unroll
            for (int j = 0; j < 4; j++) {
                const int ee = wv * 4 + j;
                GLL(kSrc + (size_t)((2 * (ss + 1) + (ee >> 3)) * 8 + (ee & 7)) * 512 + lnsw,
                    KbS[cur ^ 1] + ee * 512 + lane * 8);
            }
#pragma unroll
            for (int j = 0; j < 4; j++) {
                const int ee = wv * 4 + j;
                GLL(vSrc + (size_t)(ee * 64 + (ss + 1)) * 512 + lnsw,
                    VbS[cur ^ 1] + ee * 512 + lane * 8);
            }
        }
        __builtin_amdgcn_sched_barrier(0);

        // QK on KbS[cur]; each K fragment feeds both row-tiles
#pragma unroll
        for (int kt = 0; kt < 2; kt++) {
            const _Float16* kp = KbS[cur] + (kt * 8) * 512;
            f32x4 c0 = {0.f, 0.f, 0.f, 0.f}, c1 = {0.f, 0.f, 0.f, 0.f};
#pragma unroll
            for (int ks = 0; ks < 8; ks++) {
                f16x8 kf = *(const f16x8*)(kp + ks * 512 + lofsA);
                c0 = MFMA16(q[0][ks], kf, c0);
                c1 = MFMA16(q[1][ks], kf, c1);
            }
            const int col = kt * 16 + l15;
#pragma unroll
            for (int reg = 0; reg < 4; reg++) {
                float p0 = __expf(fminf(c0[reg], 10.5f));
                float p1 = __expf(fminf(c1[reg], 10.5f));
                ps[0][reg] += p0;
                ps[1][reg] += p1;
                pw[(quad * 4 + reg) * 40 + col] = (_Float16)p0;
                pw[(16 + quad * 4 + reg) * 40 + col] = (_Float16)p1;
            }
        }

        __builtin_amdgcn_sched_barrier(0);
        asm volatile("s_waitcnt lgkmcnt(0)" ::: "memory");   // own-wave P visible
        __builtin_amdgcn_sched_barrier(0);

        // PV on VbS[cur] (staged last substep, covered by the last barrier)
        {
            f16x8 pa0 = *(const f16x8*)(pw + l15 * 40 + quad * 8);
            f16x8 pa1 = *(const f16x8*)(pw + (16 + l15) * 40 + quad * 8);
#pragma unroll
            for (int dt = 0; dt < 16; dt++) {
                f16x8 vf = *(const f16x8*)(VbS[cur] + dt * 512 + lofsA);
                O[0][dt] = MFMA16(pa0, vf, O[0][dt]);
                O[1][dt] = MFMA16(pa1, vf, O[1][dt]);
            }
        }
        __builtin_amdgcn_sched_barrier(0);
        if (ss < 15) {
            asm volatile("s_waitcnt vmcnt(0)" ::: "memory"); // K/V(ss+1) landed
        }
        __builtin_amdgcn_s_barrier();                        // one barrier/substep
        __builtin_amdgcn_sched_barrier(0);
    }

    // psum reduce over l15 (key) axis
#pragma unroll
    for (int m = 0; m < 2; m++) {
#pragma unroll
        for (int msk = 1; msk <= 8; msk <<= 1)
#pragma unroll
            for (int reg = 0; reg < 4; reg++) ps[m][reg] += __shfl_xor(ps[m][reg], msk, 64);
        if (l15 == 0) {
#pragma unroll
            for (int reg = 0; reg < 4; reg++)
                psum4[(size_t)sk * 16384 + gr0 + m * 16 + quad * 4 + reg] = ps[m][reg];
        }
    }

    // O transpose via per-wave scratch reusing KbS (all K reads done; the
    // barrier above orders every wave past its last QK)
    _Float16* ow = &KbS[0][0] + wv * 2176;   // 16 x 136 halves per wave
#pragma unroll
    for (int m = 0; m < 2; m++) {
#pragma unroll
        for (int hd = 0; hd < 2; hd++) {
#pragma unroll
            for (int dt = 0; dt < 8; dt++) {
                const int dti = hd * 8 + dt;
#pragma unroll
                for (int reg = 0; reg < 4; reg++)
                    ow[(quad * 4 + reg) * 136 + dt * 16 + l15] = (_Float16)O[m][dti][reg];
            }
#pragma unroll
            for (int p2 = 0; p2 < 4; p2++) {
                const int u = lane + p2 * 64;
                const int row = u >> 4, col8 = u & 15;
                *(f16x8*)(Opart + ((size_t)sk * 16384 + gr0 + m * 16 + row) * 256 + hd * 128 + col8 * 8) =
                    *(const f16x8*)(ow + row * 136 + col8 * 8);
            }
        }
    }
}

// ---------------------------------------------------------------------------
// mlp_k: fused LN1+LN2+FFN1+FFN2 (+qslot | final). grid 512 x 256 threads.
// Block owns 32 rows (2 row-tiles); weight fragments shared across tiles.
// ---------------------------------------------------------------------------
__global__ __launch_bounds__(256, 2) void mlp_k(
    const _Float16* __restrict__ Opart, const float* __restrict__ psum4,
    float* __restrict__ slots,
    const float* __restrict__ ln1_g, const float* __restrict__ ln1_b,
    const float* __restrict__ ln2_g, const float* __restrict__ ln2_b,
    const _Float16* __restrict__ wf1T, const float* __restrict__ bf1,
    const _Float16* __restrict__ wf2T, const float* __restrict__ bf2,
    const _Float16* __restrict__ wqsT, const float* __restrict__ qint2,
    _Float16* __restrict__ qsT,
    const float* __restrict__ qn, const float* __restrict__ clsn,
    const float* __restrict__ alphap, const float* __restrict__ tempp,
    float* __restrict__ out, int it)
{
    __shared__ float sl[32 * 256];                 // 32KB swizzled x1/slots
    __shared__ float2 st2[32];                     // LN2 stats per row
    __shared__ __align__(16) _Float16 actL[16384]; // 32KB act tiled (swizzled)

    const int tid = threadIdx.x, lane = tid & 63, w4 = tid >> 6;
    const int l15 = lane & 15, quad = lane >> 4;
    const int lofs = l15 * 32 + quad * 8;
    const int lofsA = ((l15 * 4 + quad) ^ ((l15 >> 1) & 7)) * 8;
    const int bx = blockIdx.x;
    const int b = bx & 31, rg = bx >> 5;
    const int R0 = b * 512 + rg * 32;

    // ---- phase 1: y = slots + O/psum; x1 = LN1(y) -> sl; LN2 stats -> st2
#pragma unroll
    for (int r2 = 0; r2 < 2; r2++) {
        const int lr = w4 * 8 + r2 * 4 + quad;
        const int gr = R0 + lr;
        float l = 0.f;
#pragma unroll
        for (int j = 0; j < 4; j++) l += psum4[(size_t)j * 16384 + gr];
        const float invl = 1.f / l;
        float4 y[4];
        float sm = 0.f, sq = 0.f;
#pragma unroll
        for (int k = 0; k < 4; k++) {
            const int c = k * 64 + l15 * 4;
            float4 o4 = {0.f, 0.f, 0.f, 0.f};
#pragma unroll
            for (int j = 0; j < 4; j++) {
                f16x4 p = *(const f16x4*)(Opart + ((size_t)j * 16384 + gr) * 256 + c);
                o4.x += (float)p[0]; o4.y += (float)p[1];
                o4.z += (float)p[2]; o4.w += (float)p[3];
            }
            float4 s4 = *(const float4*)(slots + (size_t)gr * 256 + c);
            y[k].x = s4.x + o4.x * invl; y[k].y = s4.y + o4.y * invl;
            y[k].z = s4.z + o4.z * invl; y[k].w = s4.w + o4.w * invl;
            sm += y[k].x + y[k].y + y[k].z + y[k].w;
            sq += dot4f(y[k], y[k]);
        }
#pragma unroll
        for (int m = 1; m <= 8; m <<= 1) { sm += __shfl_xor(sm, m, 64); sq += __shfl_xor(sq, m, 64); }
        const float mean = sm * (1.f / 256.f);
        const float rstd = rsqrtf(sq * (1.f / 256.f) - mean * mean + 1e-5f);
        float sm2 = 0.f, sq2 = 0.f;
#pragma unroll
        for (int k = 0; k < 4; k++) {
            const int c = k * 64 + l15 * 4;
            float4 g1 = *(const float4*)(ln1_g + c);
            float4 b1 = *(const float4*)(ln1_b + c);
            float4 x1;
            x1.x = (y[k].x - mean) * rstd * g1.x + b1.x;
            x1.y = (y[k].y - mean) * rstd * g1.y + b1.y;
            x1.z = (y[k].z - mean) * rstd * g1.z + b1.z;
            x1.w = (y[k].w - mean) * rstd * g1.w + b1.w;
            *slp(sl, lr, c) = x1;
            sm2 += x1.x + x1.y + x1.z + x1.w;
            sq2 += dot4f(x1, x1);
        }
#pragma unroll
        for (int m = 1; m <= 8; m <<= 1) { sm2 += __shfl_xor(sm2, m, 64); sq2 += __shfl_xor(sq2, m, 64); }
        const float mean2 = sm2 * (1.f / 256.f);
        const float rstd2 = rsqrtf(sq2 * (1.f / 256.f) - mean2 * mean2 + 1e-5f);
        if (l15 == 0) st2[lr] = make_float2(mean2, rstd2);
    }
    __syncthreads();

    // ---- phase 2: act = gelu(LN2(x1)@Wf1+bf1); weight frags shared
    {
        f16x8 bh[2][8];
#pragma unroll
        for (int tt = 0; tt < 2; tt++) {
            const float2 s2 = st2[tt * 16 + l15];
#pragma unroll
            for (int ks = 0; ks < 8; ks++) {
                const int c0 = ks * 32 + quad * 8;
                float4 xa = *slp(sl, tt * 16 + l15, c0);
                float4 xb = *slp(sl, tt * 16 + l15, c0 + 4);
                float4 ga = *(const float4*)(ln2_g + c0);
                float4 gb = *(const float4*)(ln2_g + c0 + 4);
                float4 ba = *(const float4*)(ln2_b + c0);
                float4 bb2 = *(const float4*)(ln2_b + c0 + 4);
                bh[tt][ks][0] = (_Float16)((xa.x - s2.x) * s2.y * ga.x + ba.x);
                bh[tt][ks][1] = (_Float16)((xa.y - s2.x) * s2.y * ga.y + ba.y);
                bh[tt][ks][2] = (_Float16)((xa.z - s2.x) * s2.y * ga.z + ba.z);
                bh[tt][ks][3] = (_Float16)((xa.w - s2.x) * s2.y * ga.w + ba.w);
                bh[tt][ks][4] = (_Float16)((xb.x - s2.x) * s2.y * gb.x + bb2.x);
                bh[tt][ks][5] = (_Float16)((xb.y - s2.x) * s2.y * gb.y + bb2.y);
                bh[tt][ks][6] = (_Float16)((xb.z - s2.x) * s2.y * gb.z + bb2.z);
                bh[tt][ks][7] = (_Float16)((xb.w - s2.x) * s2.y * gb.w + bb2.w);
            }
        }
#pragma unroll 2
        for (int t8 = 0; t8 < 8; t8++) {
            const int hti = w4 * 8 + t8;
            f32x4 c0 = {0.f, 0.f, 0.f, 0.f}, c1 = {0.f, 0.f, 0.f, 0.f};
#pragma unroll
            for (int ks = 0; ks < 8; ks++) {
                f16x8 wfrag = *(const f16x8*)(wf1T + ((size_t)hti * 8 + ks) * 512 + lofs);
                c0 = MFMA16(wfrag, bh[0][ks], c0);
                c1 = MFMA16(wfrag, bh[1][ks], c1);
            }
            float4 bb = *(const float4*)(bf1 + hti * 16 + quad * 4);
            f16x4 o0, o1;
#pragma unroll
            for (int reg = 0; reg < 4; reg++) {
                float xg0 = c0[reg] + bb[reg];
                float xg1 = c1[reg] + bb[reg];
                o0[reg] = (_Float16)(0.5f * xg0 * (1.f + erff(xg0 * 0.70710678118654752f)));
                o1[reg] = (_Float16)(0.5f * xg1 * (1.f + erff(xg1 * 0.70710678118654752f)));
            }
            const int gA = l15 * 4 + (hti & 1) * 2 + (quad >> 1);
            const int aofs = ((size_t)(hti >> 1)) * 512 + ((gA ^ ((l15 >> 1) & 7)) * 8) + (quad & 1) * 4;
            *(f16x4*)(actL + aofs) = o0;
            *(f16x4*)(actL + 8192 + aofs) = o1;
        }
    }
    __syncthreads();

    // ---- phase 3: slots_new = x1 + act@Wf2 + bf2 -> sl; weight shared
    {
        f32x4 c[2][4];
#pragma unroll
        for (int tt = 0; tt < 2; tt++)
#pragma unroll
            for (int d = 0; d < 4; d++) {
                const int dti = w4 * 4 + d;
                float4 x4 = *slp(sl, tt * 16 + l15, dti * 16 + quad * 4);
                float4 bb = *(const float4*)(bf2 + dti * 16 + quad * 4);
                c[tt][d] = (f32x4){x4.x + bb.x, x4.y + bb.y, x4.z + bb.z, x4.w + bb.w};
            }
        for (int ks = 0; ks < 16; ks++) {
            f16x8 a0 = *(const f16x8*)(actL + (size_t)ks * 512 + lofsA);
            f16x8 a1 = *(const f16x8*)(actL + 8192 + (size_t)ks * 512 + lofsA);
#pragma unroll
            for (int d = 0; d < 4; d++) {
                f16x8 wfrag = *(const f16x8*)(wf2T + ((size_t)(w4 * 4 + d) * 16 + ks) * 512 + lofs);
                c[0][d] = MFMA16(wfrag, a0, c[0][d]);
                c[1][d] = MFMA16(wfrag, a1, c[1][d]);
            }
        }
        __syncthreads();
#pragma unroll
        for (int tt = 0; tt < 2; tt++)
#pragma unroll
            for (int d = 0; d < 4; d++) {
                const int dti = w4 * 4 + d;
                float4 v = {c[tt][d][0], c[tt][d][1], c[tt][d][2], c[tt][d][3]};
                *slp(sl, tt * 16 + l15, dti * 16 + quad * 4) = v;
            }
    }
    __syncthreads();

    if (it < 2) {
        // ---- phase 4a: qsT for next iteration (weight shared across tiles)
        f16x8 bs[2][8];
#pragma unroll
        for (int tt = 0; tt < 2; tt++)
#pragma unroll
            for (int ks = 0; ks < 8; ks++) {
                const int c0 = ks * 32 + quad * 8;
                float4 xa = *slp(sl, tt * 16 + l15, c0);
                float4 xb = *slp(sl, tt * 16 + l15, c0 + 4);
                bs[tt][ks][0] = (_Float16)xa.x; bs[tt][ks][1] = (_Float16)xa.y;
                bs[tt][ks][2] = (_Float16)xa.z; bs[tt][ks][3] = (_Float16)xa.w;
                bs[tt][ks][4] = (_Float16)xb.x; bs[tt][ks][5] = (_Float16)xb.y;
                bs[tt][ks][6] = (_Float16)xb.z; bs[tt][ks][7] = (_Float16)xb.w;
            }
        const int iq0 = rg * 8 + (l15 >> 2);
        const int rtg0 = b * 32 + rg * 2;
#pragma unroll
        for (int d = 0; d < 4; d++) {
            const int dti = w4 * 4 + d;
            f32x4 c0 = {0.f, 0.f, 0.f, 0.f}, c1 = {0.f, 0.f, 0.f, 0.f};
#pragma unroll
            for (int ks = 0; ks < 8; ks++) {
                f16x8 wfrag = *(const f16x8*)(wqsT + ((size_t)dti * 8 + ks) * 512 + lofs);
                c0 = MFMA16(wfrag, bs[0][ks], c0);
                c1 = MFMA16(wfrag, bs[1][ks], c1);
            }
            float4 qi0 = *(const float4*)(qint2 + (size_t)iq0 * 256 + dti * 16 + quad * 4);
            float4 qi1 = *(const float4*)(qint2 + (size_t)(iq0 + 4) * 256 + dti * 16 + quad * 4);
            f16x4 o0, o1;
#pragma unroll
            for (int reg = 0; reg < 4; reg++) {
                o0[reg] = (_Float16)((c0[reg] + qi0[reg]) * 0.0625f);
                o1[reg] = (_Float16)((c1[reg] + qi1[reg]) * 0.0625f);
            }
            const int qofs = (dti >> 1) * 512 + l15 * 32
                           + ((dti & 1) * 2 + (quad >> 1)) * 8 + (quad & 1) * 4;
            *(f16x4*)(qsT + (size_t)rtg0 * 4096 + qofs) = o0;
            *(f16x4*)(qsT + (size_t)(rtg0 + 1) * 4096 + qofs) = o1;
        }
        // ---- phase 4b: slots_new -> global (coalesced)
        {
            const int lr2 = tid >> 3, k8 = tid & 7;
#pragma unroll
            for (int q4 = 0; q4 < 8; q4++) {
                float4 v = *slp(sl, lr2, k8 * 32 + q4 * 4);
                *(float4*)(slots + (size_t)(R0 + lr2) * 256 + k8 * 32 + q4 * 4) = v;
            }
        }
    } else {
        // ---- phase 4c: final scoring (2 intents per wave, 8 per block)
#pragma unroll
        for (int ii = 0; ii < 2; ii++) {
            const int i_loc = w4 * 2 + ii;
            const int i = rg * 8 + i_loc;
            float4 qv = *(const float4*)(qn + (size_t)i * 256 + lane * 4);
            float4 xs[4];
            float st4[4];
#pragma unroll
            for (int n = 0; n < 4; n++) {
                xs[n] = *slp(sl, i_loc * 4 + n, lane * 4);
                float ss = dot4f(xs[n], xs[n]);
                float sq = dot4f(xs[n], qv);
#pragma unroll
                for (int m = 1; m < 64; m <<= 1) { ss += __shfl_xor(ss, m, 64); sq += __shfl_xor(sq, m, 64); }
                st4[n] = sq / fmaxf(sqrtf(ss), 1e-12f);
            }
            float mx = fmaxf(fmaxf(st4[0], st4[1]), fmaxf(st4[2], st4[3]));
            float e0 = __expf(st4[0] - mx), e1 = __expf(st4[1] - mx);
            float e2 = __expf(st4[2] - mx), e3 = __expf(st4[3] - mx);
            float inv = 1.f / (e0 + e1 + e2 + e3);
            float4 smv;
            smv.x = (e0 * xs[0].x + e1 * xs[1].x + e2 * xs[2].x + e3 * xs[3].x) * inv;
            smv.y = (e0 * xs[0].y + e1 * xs[1].y + e2 * xs[2].y + e3 * xs[3].y) * inv;
            smv.z = (e0 * xs[0].z + e1 * xs[1].z + e2 * xs[2].z + e3 * xs[3].z) * inv;
            smv.w = (e0 * xs[0].w + e1 * xs[1].w + e2 * xs[2].w + e3 * xs[3].w) * inv;
            float ssm = dot4f(smv, smv);
            float sqn = dot4f(smv, qv);
            float4 cv = *(const float4*)(clsn + (size_t)b * 256 + lane * 4);
            float cq = dot4f(cv, qv);
#pragma unroll
            for (int m = 1; m < 64; m <<= 1) {
                ssm += __shfl_xor(ssm, m, 64);
                sqn += __shfl_xor(sqn, m, 64);
                cq  += __shfl_xor(cq,  m, 64);
            }
            if (lane == 0) {
                float score = cq + alphap[0] * sqn / fmaxf(sqrtf(ssm), 1e-12f);
                out[(size_t)b * NI + i] = score / fmaxf(tempp[0], 1e-4f);
            }
        }
    }
}

// ---------------------------------------------------------------------------
extern "C" void kernel_launch(void* const* d_in, const int* in_sizes, int n_in,
                              void* d_out, int out_size, void* d_ws, size_t ws_size,
                              hipStream_t stream)
{
    const float* tokens     = (const float*)d_in[0];
    const float* cls_embed  = (const float*)d_in[1];
    const float* intent_q   = (const float*)d_in[2];
    const float* noise      = (const float*)d_in[3];
    const float* Wk  = (const float*)d_in[4];
    const float* bk  = (const float*)d_in[5];
    const float* Wv  = (const float*)d_in[6];
    const float* bv  = (const float*)d_in[7];
    const float* Wqs = (const float*)d_in[8];
    const float* bqs = (const float*)d_in[9];
    const float* Wqi = (const float*)d_in[10];
    const float* bqi = (const float*)d_in[11];
    const float* ln1g = (const float*)d_in[12];
    const float* ln1b = (const float*)d_in[13];
    const float* ln2g = (const float*)d_in[14];
    const float* ln2b = (const float*)d_in[15];
    const float* Wf1 = (const float*)d_in[16];
    const float* bf1 = (const float*)d_in[17];
    const float* Wf2 = (const float*)d_in[18];
    const float* bf2 = (const float*)d_in[19];
    const float* slot_mu    = (const float*)d_in[20];
    const float* slot_sigma = (const float*)d_in[21];
    const float* alphap = (const float*)d_in[22];
    const float* tempp  = (const float*)d_in[23];
    float* out = (float*)d_out;

    char* base = (char*)d_ws;
    _Float16* qsT   = (_Float16*)(base);                        //  8388608 B
    _Float16* kT    = (_Float16*)(base + 33554432u);            // 33554432 B
    _Float16* vT    = (_Float16*)(base + 67108864u);            // 33554432 B
    _Float16* Opart = (_Float16*)(base + 100663296u);           // 33554432 B
    float* slots    = (float*)(base + 134217728u);              // 16777216 B
    _Float16* wkT   = (_Float16*)(base + 150994944u);           //   131072 B
    _Float16* wvT   = (_Float16*)(base + 151126016u);
    _Float16* wqsT  = (_Float16*)(base + 151257088u);
    _Float16* wf1T  = (_Float16*)(base + 151388160u);           //   262144 B
    _Float16* wf2T  = (_Float16*)(base + 151650304u);           //   262144 B
    float* qint2    = (float*)(base + 151912448u);              //   131072 B
    float* qnb      = (float*)(base + 152043520u);              //   131072 B
    float* clsn     = (float*)(base + 152174592u);              //    32768 B
    float* psum4    = (float*)(base + 152207360u);              //   262144 B

    prep<<<272, 256, 0, stream>>>(Wk, Wv, Wqs, Wf1, Wf2, intent_q, Wqi, bqi, bqs,
                                  cls_embed, wkT, wvT, wqsT, wf1T, wf2T,
                                  qint2, qnb, clsn);
    kvf_k<<<256, 512, 0, stream>>>(tokens, wkT, wvT, bk, bv, kT, vT);
    slotq_k<<<1024, 256, 0, stream>>>(noise, slot_mu, slot_sigma, wqsT, qint2,
                                      slots, qsT);

    for (int it = 0; it < 3; it++) {
        attn_k<<<512, 256, 0, stream>>>(qsT, kT, vT, Opart, psum4);
        mlp_k<<<512, 256, 0, stream>>>(Opart, psum4, slots,
                                       ln1g, ln1b, ln2g, ln2b,
                                       wf1T, bf1, wf2T, bf2,
                                       wqsT, qint2, qsT,
                                       qnb, clsn, alphap, tempp, out, it);
    }
}